// Round 6
// baseline (728.094 us; speedup 1.0000x reference)
//
#include <hip/hip_runtime.h>
#include <math.h>

#define N_B 64
#define T_LEN 1024
#define IN_D 4
#define CH 5
#define SIG 780
#define KP 800           // padded K for f16 planes
#define SEG_LEN 16
#define N_SEG 64
// level offsets: L1:0, L2:5, L3:30, L4:155
#define SC_L1 1.0f
#define SC_L2 0.25f
#define SC_L3 0.0625f
#define SC_L4 0.015625f

typedef _Float16 f16x8 __attribute__((ext_vector_type(8)));
typedef float f32x4 __attribute__((ext_vector_type(4)));

typedef __attribute__((address_space(1))) const void* as1cp;
typedef __attribute__((address_space(3))) void* as3p;

#define VMCNT(n) asm volatile("s_waitcnt vmcnt(" #n ")" ::: "memory")

__device__ __forceinline__ float fast_tanh(float x) {
  float ax = fabsf(x);
  float e = __expf(-2.0f * ax);
  float r = (1.0f - e) * __builtin_amdgcn_rcpf(1.0f + e);
  return copysignf(r, x);
}

// ---------------- Kernel 1 (fallback only): time-aug + pointwise conv -------
__global__ __launch_bounds__(256) void conv_kernel(
    const float* __restrict__ batch,
    const float* __restrict__ conv_w,
    const float* __restrict__ conv_b,
    float* __restrict__ b_out) {
  int idx = blockIdx.x * blockDim.x + threadIdx.x;
  if (idx >= N_B * T_LEN) return;
  int t = idx & (T_LEN - 1);
  const float* a = batch + (size_t)idx * IN_D;
  float a0 = a[0], a1 = a[1], a2 = a[2], a3 = a[3];
  float tm = (float)(t + 1) / (float)T_LEN;
  float* o = b_out + (size_t)idx * CH;
#pragma unroll
  for (int j = 0; j < CH; ++j) {
    const float* w = conv_w + j * CH;
    float r = conv_b[j];
    r = fmaf(tm, w[4], r);
    r = fmaf(a3, w[3], r);
    r = fmaf(a2, w[2], r);
    r = fmaf(a1, w[1], r);
    r = fmaf(a0, w[0], r);
    o[j] = r;
  }
}

// ---------------- Signature phase A: per-segment signatures (conv fused) ----
// Ping-pong LDS state: 1 barrier per time-step.
__global__ __launch_bounds__(320) void seg_kernel(
    const float* __restrict__ batch,
    const float* __restrict__ conv_w,
    const float* __restrict__ conv_b,
    float* __restrict__ P) {
  int s = blockIdx.x;
  int n = blockIdx.y;
  int tid = threadIdx.x;

  __shared__ float S[2][SIG];
  __shared__ float bc[(SEG_LEN + 1) * CH];
  __shared__ float dsh[SEG_LEN][CH];

  for (int i = tid; i < SIG; i += 320) S[0][i] = 0.0f;
  if (tid < (SEG_LEN + 1) * CH) {
    int r = s * SEG_LEN - 1 + tid / CH, ch = tid % CH;
    float v = 0.0f;
    if (r >= 0) {
      const float* a = batch + ((size_t)n * T_LEN + r) * IN_D;
      const float* w = conv_w + ch * CH;
      v = conv_b[ch];
      v = fmaf(a[0], w[0], v);
      v = fmaf(a[1], w[1], v);
      v = fmaf(a[2], w[2], v);
      v = fmaf(a[3], w[3], v);
      v = fmaf((float)(r + 1) * (1.0f / T_LEN), w[4], v);
    }
    bc[tid] = v;
  }
  __syncthreads();
  if (tid < SEG_LEN * CH) {
    int j = tid / CH, ch = tid % CH;
    dsh[j][ch] = bc[(j + 1) * CH + ch] - bc[j * CH + ch];
  }

  const int x0 = tid;
  const int x1 = tid + 320;
  const bool has1 = (tid < 305);
  const int a0i = x0 / 125, b0i = (x0 / 25) % 5, c0i = (x0 / 5) % 5, d0i = x0 % 5;
  const int a1i = x1 / 125, b1i = (x1 / 25) % 5, c1i = (x1 / 5) % 5, d1i = x1 % 5;
  const int s2_0 = x0 / 25, s3_0 = x0 / 5;
  const int s2_1 = x1 / 25, s3_1 = x1 / 5;
  const bool hasL3 = (tid < 125);
  const int ya = tid / 25, yb = (tid / 5) % 5, yc = tid % 5;
  const bool hasL2 = (tid < 25);
  const int za = tid / 5, zb = tid % 5;
  const bool hasL1 = (tid < CH);
  __syncthreads();

  int c = 0;
  for (int j = 0; j < SEG_LEN; ++j) {
    const float* Sc = S[c];
    float* Sn = S[c ^ 1];
    float n4_0, n4_1 = 0.0f, n3 = 0.0f, n2 = 0.0f, n1 = 0.0f;
    {
      float tH = fmaf(0.25f, dsh[j][a0i], Sc[a0i]);
      tH = fmaf((1.0f / 3.0f) * dsh[j][b0i], tH, Sc[5 + s2_0]);
      tH = fmaf(0.5f * dsh[j][c0i], tH, Sc[30 + s3_0]);
      n4_0 = fmaf(dsh[j][d0i], tH, Sc[155 + x0]);
    }
    if (has1) {
      float tH = fmaf(0.25f, dsh[j][a1i], Sc[a1i]);
      tH = fmaf((1.0f / 3.0f) * dsh[j][b1i], tH, Sc[5 + s2_1]);
      tH = fmaf(0.5f * dsh[j][c1i], tH, Sc[30 + s3_1]);
      n4_1 = fmaf(dsh[j][d1i], tH, Sc[155 + x1]);
    }
    if (hasL3) {
      float tH = fmaf((1.0f / 3.0f), dsh[j][ya], Sc[ya]);
      tH = fmaf(0.5f * dsh[j][yb], tH, Sc[5 + ya * 5 + yb]);
      n3 = fmaf(dsh[j][yc], tH, Sc[30 + tid]);
    }
    if (hasL2) {
      float tH = fmaf(0.5f, dsh[j][za], Sc[za]);
      n2 = fmaf(dsh[j][zb], tH, Sc[5 + tid]);
    }
    if (hasL1) n1 = Sc[tid] + dsh[j][tid];
    Sn[155 + x0] = n4_0;
    if (has1) Sn[155 + x1] = n4_1;
    if (hasL3) Sn[30 + tid] = n3;
    if (hasL2) Sn[5 + tid] = n2;
    if (hasL1) Sn[tid] = n1;
    __syncthreads();
    c ^= 1;
  }

  float* Pr = P + ((size_t)n * N_SEG + s) * SIG;
  for (int i = tid; i < SIG; i += 320) Pr[i] = S[c][i];
}

// ---------------- Signature phase B: sequential prefix (ping-pong, 1 bar) ---
__global__ __launch_bounds__(640) void prefix_kernel(float* __restrict__ P) {
  int n = blockIdx.x;
  int tid = threadIdx.x;
  __shared__ float A[2][SIG];
  __shared__ float Bs[SIG];

  float* Pn = P + (size_t)n * N_SEG * SIG;
  for (int i = tid; i < SIG; i += 640) A[0][i] = Pn[i];
  int i0 = tid, i1 = tid + 640;
  float r0 = 0.f, r1 = 0.f;
  if (i0 < SIG) r0 = Pn[SIG + i0];
  if (i1 < SIG) r1 = Pn[SIG + i1];

  const int e4 = tid;
  const int q4a = e4 / 125, r125 = e4 % 125, r25 = e4 % 25, r5 = e4 % 5;
  const int e4d5 = e4 / 5, e4d25 = e4 / 25;
  const int e3 = tid;
  const int e3a = e3 / 25, e3r25 = e3 % 25, e3r5 = e3 % 5, e3d5 = e3 / 5;
  const int e2 = tid - 125;
  const int e1 = tid - 150;

  int c = 0;
  for (int s = 1; s < N_SEG; ++s) {
    if (i0 < SIG) Bs[i0] = r0;
    if (i1 < SIG) Bs[i1] = r1;
    __syncthreads();   // Bs ready; prev iter's A[c] writes visible
    if (s + 1 < N_SEG) {
      const float* Pnx = Pn + (size_t)(s + 1) * SIG;
      if (i0 < SIG) r0 = Pnx[i0];
      if (i1 < SIG) r1 = Pnx[i1];
    }
    const float* Ac = A[c];
    float* An = A[c ^ 1];
    float* Po = Pn + (size_t)s * SIG;
    if (tid < 625) {
      float v4 = Ac[155 + e4] + Bs[155 + e4];
      v4 = fmaf(Ac[30 + e4d5], Bs[r5], v4);
      v4 = fmaf(Ac[5 + e4d25], Bs[5 + r25], v4);
      v4 = fmaf(Ac[q4a], Bs[30 + r125], v4);
      An[155 + e4] = v4; Po[155 + e4] = v4;
    }
    if (tid < 125) {
      float v3 = Ac[30 + e3] + Bs[30 + e3];
      v3 = fmaf(Ac[5 + e3d5], Bs[e3r5], v3);
      v3 = fmaf(Ac[e3a], Bs[5 + e3r25], v3);
      An[30 + e3] = v3; Po[30 + e3] = v3;
    } else if (tid < 150) {
      float v2 = Ac[5 + e2] + Bs[5 + e2];
      v2 = fmaf(Ac[e2 / 5], Bs[e2 % 5], v2);
      An[5 + e2] = v2; Po[5 + e2] = v2;
    } else if (tid < 155) {
      float v1 = Ac[e1] + Bs[e1];
      An[e1] = v1; Po[e1] = v1;
    }
    c ^= 1;
  }
}

// ---------------- Signature phase C: stream + emit f16 planes ----------------
// Ping-pong S and row buffers: 1 barrier per time-step; store of row t-1
// overlaps iteration t's compute.
__global__ __launch_bounds__(320) void emit_kernel(
    const float* __restrict__ batch,
    const float* __restrict__ conv_w,
    const float* __restrict__ conv_b,
    const float* __restrict__ P,
    _Float16* __restrict__ c1,
    _Float16* __restrict__ c2) {
  int s = blockIdx.x;
  int n = blockIdx.y;
  int tid = threadIdx.x;

  __shared__ float S[2][SIG];
  __shared__ float bc[(SEG_LEN + 1) * CH];
  __shared__ float dsh[SEG_LEN][CH];
  __shared__ __align__(16) _Float16 row1[2][KP];
  __shared__ __align__(16) _Float16 row2[2][KP];

  if (s == 0) {
    for (int i = tid; i < SIG; i += 320) S[0][i] = 0.0f;
  } else {
    const float* Pr = P + ((size_t)n * N_SEG + (s - 1)) * SIG;
    for (int i = tid; i < SIG; i += 320) S[0][i] = Pr[i];
  }
  if (tid < (SEG_LEN + 1) * CH) {
    int r = s * SEG_LEN - 1 + tid / CH, ch = tid % CH;
    float v = 0.0f;
    if (r >= 0) {
      const float* a = batch + ((size_t)n * T_LEN + r) * IN_D;
      const float* w = conv_w + ch * CH;
      v = conv_b[ch];
      v = fmaf(a[0], w[0], v);
      v = fmaf(a[1], w[1], v);
      v = fmaf(a[2], w[2], v);
      v = fmaf(a[3], w[3], v);
      v = fmaf((float)(r + 1) * (1.0f / T_LEN), w[4], v);
    }
    bc[tid] = v;
  }
  if (tid < KP - SIG) {  // zero the pad tails once (both ping-pong buffers)
    row1[0][SIG + tid] = (_Float16)0.0f;
    row1[1][SIG + tid] = (_Float16)0.0f;
    row2[0][SIG + tid] = (_Float16)0.0f;
    row2[1][SIG + tid] = (_Float16)0.0f;
  }
  __syncthreads();
  if (tid < SEG_LEN * CH) {
    int j = tid / CH, ch = tid % CH;
    dsh[j][ch] = bc[(j + 1) * CH + ch] - bc[j * CH + ch];
  }

  const int x0 = tid;
  const int x1 = tid + 320;
  const bool has1 = (tid < 305);
  const int a0i = x0 / 125, b0i = (x0 / 25) % 5, c0i = (x0 / 5) % 5, d0i = x0 % 5;
  const int a1i = x1 / 125, b1i = (x1 / 25) % 5, c1i = (x1 / 5) % 5, d1i = x1 % 5;
  const int s2_0 = x0 / 25, s3_0 = x0 / 5;
  const int s2_1 = x1 / 25, s3_1 = x1 / 5;
  const bool hasL3 = (tid < 125);
  const int ya = tid / 25, yb = (tid / 5) % 5, yc = tid % 5;
  const bool hasL2 = (tid < 25);
  const int za = tid / 5, zb = tid % 5;
  const bool hasL1 = (tid < CH);
  __syncthreads();

  int c = 0;
  for (int j = 0; j < SEG_LEN; ++j) {
    int t = s * SEG_LEN + j;
    const float* Sc = S[c];
    float* Sn = S[c ^ 1];
    float n4_0, n4_1 = 0.0f, n3 = 0.0f, n2 = 0.0f, n1 = 0.0f;
    {
      float tH = fmaf(0.25f, dsh[j][a0i], Sc[a0i]);
      tH = fmaf((1.0f / 3.0f) * dsh[j][b0i], tH, Sc[5 + s2_0]);
      tH = fmaf(0.5f * dsh[j][c0i], tH, Sc[30 + s3_0]);
      n4_0 = fmaf(dsh[j][d0i], tH, Sc[155 + x0]);
    }
    if (has1) {
      float tH = fmaf(0.25f, dsh[j][a1i], Sc[a1i]);
      tH = fmaf((1.0f / 3.0f) * dsh[j][b1i], tH, Sc[5 + s2_1]);
      tH = fmaf(0.5f * dsh[j][c1i], tH, Sc[30 + s3_1]);
      n4_1 = fmaf(dsh[j][d1i], tH, Sc[155 + x1]);
    }
    if (hasL3) {
      float tH = fmaf((1.0f / 3.0f), dsh[j][ya], Sc[ya]);
      tH = fmaf(0.5f * dsh[j][yb], tH, Sc[5 + ya * 5 + yb]);
      n3 = fmaf(dsh[j][yc], tH, Sc[30 + tid]);
    }
    if (hasL2) {
      float tH = fmaf(0.5f, dsh[j][za], Sc[za]);
      n2 = fmaf(dsh[j][zb], tH, Sc[5 + tid]);
    }
    if (hasL1) n1 = Sc[tid] + dsh[j][tid];

    // overlapped store of the PREVIOUS row (completed at last barrier)
    if (j > 0) {
      size_t base = ((size_t)n * T_LEN + (t - 1)) * KP;
      if (tid < 100) {
        *(float4*)(c1 + base + tid * 8) = *(const float4*)&row1[c][tid * 8];
      } else if (tid < 200) {
        int cc = tid - 100;
        *(float4*)(c2 + base + cc * 8) = *(const float4*)&row2[c][cc * 8];
      }
    }

    // commit state + build scaled f16 row into the OTHER buffers
    Sn[155 + x0] = n4_0;
    if (has1) Sn[155 + x1] = n4_1;
    if (hasL3) Sn[30 + tid] = n3;
    if (hasL2) Sn[5 + tid] = n2;
    if (hasL1) Sn[tid] = n1;

    float z = (t == 0) ? 0.0f : 1.0f;
    {
      float v = n4_0 * SC_L4 * z;
      _Float16 h = (_Float16)v;
      row1[c ^ 1][155 + x0] = h; row2[c ^ 1][155 + x0] = (_Float16)(v - (float)h);
    }
    if (has1) {
      float v = n4_1 * SC_L4 * z;
      _Float16 h = (_Float16)v;
      row1[c ^ 1][155 + x1] = h; row2[c ^ 1][155 + x1] = (_Float16)(v - (float)h);
    }
    if (hasL3) {
      float v = n3 * SC_L3 * z;
      _Float16 h = (_Float16)v;
      row1[c ^ 1][30 + tid] = h; row2[c ^ 1][30 + tid] = (_Float16)(v - (float)h);
    }
    if (hasL2) {
      float v = n2 * SC_L2 * z;
      _Float16 h = (_Float16)v;
      row1[c ^ 1][5 + tid] = h; row2[c ^ 1][5 + tid] = (_Float16)(v - (float)h);
    }
    if (hasL1) {
      float v = n1 * SC_L1 * z;
      _Float16 h = (_Float16)v;
      row1[c ^ 1][tid] = h; row2[c ^ 1][tid] = (_Float16)(v - (float)h);
    }
    __syncthreads();
    c ^= 1;
  }
  // final row (t = s*SEG_LEN + 15)
  {
    size_t base = ((size_t)n * T_LEN + (s * SEG_LEN + SEG_LEN - 1)) * KP;
    if (tid < 100) {
      *(float4*)(c1 + base + tid * 8) = *(const float4*)&row1[c][tid * 8];
    } else if (tid < 200) {
      int cc = tid - 100;
      *(float4*)(c2 + base + cc * 8) = *(const float4*)&row2[c][cc * 8];
    }
  }
}

// ---------------- W plane conversion (scaled, padded to 896x800) -------------
__global__ __launch_bounds__(256) void wconv_kernel(
    const float* __restrict__ W,
    _Float16* __restrict__ w1,
    _Float16* __restrict__ w2) {
  int idx = blockIdx.x * blockDim.x + threadIdx.x;
  if (idx >= 896 * KP) return;
  int nn = idx / KP, k = idx % KP;
  float v = 0.0f;
  if (nn < SIG && k < SIG) {
    float sc = (k < 5) ? 1.0f : (k < 30) ? 4.0f : (k < 155) ? 16.0f : 64.0f;
    v = W[(size_t)nn * SIG + k] * sc;
  }
  _Float16 h = (_Float16)v;
  w1[idx] = h;
  w2[idx] = (_Float16)(v - (float)h);
}

// ---------------- MFMA GEMM: out = tanh((c1+c2)*(w1+w2)^T + b) ---------------
// Round 6: same round-1 schedule (3 bufs, counted VMCNT, prefetch depth 2) but
// tile shrunk to 128x64 so LDS = 72 KB -> TWO blocks/CU (was 1 at 144 KB).
// Cross-block overlap covers the per-K-step barrier/wait stalls (m114 effect)
// that cap the 1-block/CU structure at ~32% MfmaUtil. FLOP:staging-byte ratio
// is unchanged (1/(1/128+1/64) == 1/(1/256+1/128)). 8 waves (2m x 4n),
// per-wave 64x16 = acc[4], 12 MFMA/wave/K-step, 3 loads/thread/K-step.
// N=896=14*64 exact; grid 7168 = 8*896 keeps the XCD-bijective swizzle: all
// 14 n-siblings of an m-tile stay on one XCD (A stays L2-resident).
__global__ __launch_bounds__(512, 4) void gemm_mfma(
    const _Float16* __restrict__ A1p, const _Float16* __restrict__ A2p,
    const _Float16* __restrict__ B1p, const _Float16* __restrict__ B2p,
    const float* __restrict__ bias, float* __restrict__ out) {
  __shared__ _Float16 Al[3][2][128 * 32];  // 3 bufs x 2 planes x 8 KB = 48 KB
  __shared__ _Float16 Bl[3][2][64 * 32];   // 3 bufs x 2 planes x 4 KB = 24 KB

  int tid = threadIdx.x;
  int lane = tid & 63, wid = tid >> 6;
  int wm = wid >> 2, wn = wid & 3;     // 2m x 4n

  int b = blockIdx.x;
  int xcd = b & 7, sidx = b >> 3;      // 7168 = 8 * 896; 896 = 64 * 14
  int mt = (sidx / 14) * 8 + xcd;      // 0..511, bijective
  int nt = sidx % 14;
  int m0 = mt * 128;
  int n0 = nt * 64;

  f32x4 acc[4];
#pragma unroll
  for (int i = 0; i < 4; ++i) acc[i] = (f32x4){0.f, 0.f, 0.f, 0.f};

  int sr = lane >> 2, scn = lane & 3;
  int swst = (sr ^ (sr >> 2)) & 3;
  int qg = scn ^ swst;          // pre-swizzled global chunk (LDS stays linear)
  int fr = lane & 15, fq = lane >> 4;
  int swf = (fr ^ (fr >> 2)) & 3;
  int fchunk = fq ^ swf;        // matching read-side swizzle

  auto stageA = [&](int kb, int buf, int i) {
    int k0 = kb * 32;
    int linear = wid * 2 + i;          // 0..15
    int plane = linear >> 3, grp = linear & 7;
    size_t g = (size_t)(m0 + grp * 16 + sr) * KP + k0 + qg * 8;
    const _Float16* src = (plane ? A2p : A1p) + g;
    __builtin_amdgcn_global_load_lds((as1cp)src, (as3p)(&Al[buf][plane][grp * 512]), 16, 0, 0);
  };
  auto stageB = [&](int kb, int buf) {
    int k0 = kb * 32;
    int plane = wid >> 2, grp = wid & 3;  // 8 waves cover 2 planes x 4 groups
    size_t g = (size_t)(n0 + grp * 16 + sr) * KP + k0 + qg * 8;
    const _Float16* src = (plane ? B2p : B1p) + g;
    __builtin_amdgcn_global_load_lds((as1cp)src, (as3p)(&Bl[buf][plane][grp * 512]), 16, 0, 0);
  };

  // prologue: tiles 0 and 1 in flight (6 loads/thread)
#pragma unroll
  for (int i = 0; i < 2; ++i) stageA(0, 0, i);
  stageB(0, 0);
#pragma unroll
  for (int i = 0; i < 2; ++i) stageA(1, 1, i);
  stageB(1, 1);

  int cur = 0;
#pragma unroll 1
  for (int kb = 0; kb < 25; ++kb) {
    int nx = cur + 2; if (nx >= 3) nx -= 3;
    bool pf = (kb + 2 < 25);
    // counted wait: tile kb's 3 loads done, tile kb+1's 3 stay in flight
    if (kb < 24) { VMCNT(3); } else { VMCNT(0); }
    __builtin_amdgcn_s_barrier();
    __builtin_amdgcn_sched_barrier(0);
    f16x8 a1f[4], a2f[4], b1f, b2f;
#pragma unroll
    for (int tm = 0; tm < 4; ++tm) {
      int off = (wm * 64 + tm * 16 + fr) * 32 + fchunk * 8;
      a1f[tm] = *(const f16x8*)&Al[cur][0][off];
      a2f[tm] = *(const f16x8*)&Al[cur][1][off];
    }
    {
      int off = (wn * 16 + fr) * 32 + fchunk * 8;
      b1f = *(const f16x8*)&Bl[cur][0][off];
      b2f = *(const f16x8*)&Bl[cur][1][off];
    }
    if (pf) {  // issue next-next tile loads; they ride across barriers
      stageA(kb + 2, nx, 0);
      stageA(kb + 2, nx, 1);
      stageB(kb + 2, nx);
    }
    __builtin_amdgcn_s_barrier();
    __builtin_amdgcn_sched_barrier(0);
    __builtin_amdgcn_s_setprio(1);
#pragma unroll
    for (int tm = 0; tm < 4; ++tm) {
      acc[tm] = __builtin_amdgcn_mfma_f32_16x16x32_f16(a1f[tm], b1f, acc[tm], 0, 0, 0);
      acc[tm] = __builtin_amdgcn_mfma_f32_16x16x32_f16(a1f[tm], b2f, acc[tm], 0, 0, 0);
      acc[tm] = __builtin_amdgcn_mfma_f32_16x16x32_f16(a2f[tm], b1f, acc[tm], 0, 0, 0);
    }
    __builtin_amdgcn_s_setprio(0);
    cur = cur + 1; if (cur >= 3) cur -= 3;
  }
  __syncthreads();  // all frag reads done; LDS reusable for epilogue

  // epilogue: bias + fast tanh, per-wave LDS transpose (32x20 f32), stores
  float* ep = (float*)(&Al[0][0][0]) + wid * 640;  // 8 waves x 2560 B = 20 KB

  float bv;
  {
    int nn = n0 + wn * 16 + fr;
    bv = (nn < SIG) ? bias[nn] : 0.0f;
  }
#pragma unroll
  for (int h = 0; h < 2; ++h) {
#pragma unroll
    for (int tm2 = 0; tm2 < 2; ++tm2) {
      int tm = h * 2 + tm2;
#pragma unroll
      for (int r = 0; r < 4; ++r) {
        int lr = tm2 * 16 + fq * 4 + r;  // 0..31
        ep[lr * 20 + fr] = fast_tanh(acc[tm][r] + bv);
      }
    }
    // wave-synchronous readout: 32 rows x 16 cols; lanes 0-31 cols 0-7,
    // lanes 32-63 cols 8-15, float4 per 4 cols
    __builtin_amdgcn_sched_barrier(0);
#pragma unroll
    for (int q = 0; q < 2; ++q) {
      int lr = lane & 31;
      int c0 = (lane >> 5) * 8 + q * 4;        // 0,4,8,12
      int gm = m0 + wm * 64 + h * 32 + lr;
      int col = n0 + wn * 16 + c0;
      if (col + 3 < SIG) {
        *(float4*)(out + (size_t)gm * SIG + col) =
            *(const float4*)&ep[lr * 20 + c0];
      } else if (col < SIG) {
#pragma unroll
        for (int e = 0; e < 4; ++e) {
          int c2 = col + e;
          if (c2 < SIG) out[(size_t)gm * SIG + c2] = ep[lr * 20 + c0 + e];
        }
      }
    }
    __builtin_amdgcn_sched_barrier(0);
  }
}

// ================= FALLBACK PATH (round-1, fp32) =============================
__global__ __launch_bounds__(320) void sig_kernel_fb(
    const float* __restrict__ b_in, float* __restrict__ c_out) {
  int n = blockIdx.x;
  int tid = threadIdx.x;
  __shared__ float S[SIG];
  __shared__ float bc[64 * CH];
  __shared__ float dsh[CH];
  __shared__ float pb[CH];
  for (int i = tid; i < SIG; i += 320) S[i] = 0.0f;
  if (tid < CH) pb[tid] = 0.0f;
  const float* bn = b_in + (size_t)n * T_LEN * CH;
  float* cn = c_out + (size_t)n * T_LEN * SIG;
  const int x0 = tid, x1 = tid + 320;
  const bool has1 = (tid < 305);
  const int a0i = x0 / 125, b0i = (x0 / 25) % 5, c0i = (x0 / 5) % 5, d0i = x0 % 5;
  const int a1i = x1 / 125, b1i = (x1 / 25) % 5, c1i = (x1 / 5) % 5, d1i = x1 % 5;
  const int s2_0 = x0 / 25, s3_0 = x0 / 5, s2_1 = x1 / 25, s3_1 = x1 / 5;
  const bool hasL3 = (tid < 125);
  const int ya = tid / 25, yb = (tid / 5) % 5, yc = tid % 5;
  const bool hasL2 = (tid < 25);
  const int za = tid / 5, zb = tid % 5;
  const bool hasL1 = (tid < CH);
  for (int t = 0; t < T_LEN; ++t) {
    if ((t & 63) == 0) {
      __syncthreads();
      bc[tid] = bn[t * CH + tid];
      __syncthreads();
    }
    if (tid < CH) {
      float cur = bc[(t & 63) * CH + tid];
      dsh[tid] = cur - pb[tid];
      pb[tid] = cur;
    }
    __syncthreads();
    float n4_0, n4_1 = 0.0f, n3 = 0.0f, n2 = 0.0f, n1 = 0.0f;
    {
      float tH = fmaf(0.25f, dsh[a0i], S[a0i]);
      tH = fmaf((1.0f / 3.0f) * dsh[b0i], tH, S[5 + s2_0]);
      tH = fmaf(0.5f * dsh[c0i], tH, S[30 + s3_0]);
      n4_0 = fmaf(dsh[d0i], tH, S[155 + x0]);
    }
    if (has1) {
      float tH = fmaf(0.25f, dsh[a1i], S[a1i]);
      tH = fmaf((1.0f / 3.0f) * dsh[b1i], tH, S[5 + s2_1]);
      tH = fmaf(0.5f * dsh[c1i], tH, S[30 + s3_1]);
      n4_1 = fmaf(dsh[d1i], tH, S[155 + x1]);
    }
    if (hasL3) {
      float tH = fmaf((1.0f / 3.0f), dsh[ya], S[ya]);
      tH = fmaf(0.5f * dsh[yb], tH, S[5 + ya * 5 + yb]);
      n3 = fmaf(dsh[yc], tH, S[30 + tid]);
    }
    if (hasL2) {
      float tH = fmaf(0.5f, dsh[za], S[za]);
      n2 = fmaf(dsh[zb], tH, S[5 + tid]);
    }
    if (hasL1) n1 = S[tid] + dsh[tid];
    __syncthreads();
    S[155 + x0] = n4_0;
    if (has1) S[155 + x1] = n4_1;
    if (hasL3) S[30 + tid] = n3;
    if (hasL2) S[5 + tid] = n2;
    if (hasL1) S[tid] = n1;
    float* crow = cn + (size_t)t * SIG;
    float z = (t == 0) ? 0.0f : 1.0f;
    crow[155 + x0] = n4_0 * z;
    if (has1) crow[155 + x1] = n4_1 * z;
    if (hasL3) crow[30 + tid] = n3 * z;
    if (hasL2) crow[5 + tid] = n2 * z;
    if (hasL1) crow[tid] = n1 * z;
    __syncthreads();
  }
}

#define BM 256
#define BN 64
#define BK 16
__global__ __launch_bounds__(256) void gemm_tanh_fb(
    const float* __restrict__ Cmat, const float* __restrict__ W,
    const float* __restrict__ bias, float* __restrict__ out) {
  __shared__ float As[BK][BM + 4];
  __shared__ float Ws[BK][BN + 4];
  int tid = threadIdx.x;
  int tx = tid & 7, ty = tid >> 3;
  int m0 = blockIdx.x * BM, n0 = blockIdx.y * BN;
  float acc[8][8];
#pragma unroll
  for (int i = 0; i < 8; ++i)
#pragma unroll
    for (int j = 0; j < 8; ++j) acc[i][j] = 0.0f;
  for (int kb = 0; kb < SIG; kb += BK) {
    __syncthreads();
#pragma unroll
    for (int p = 0; p < 4; ++p) {
      int id = tid + p * 256;
      int row = id >> 2, kg = (id & 3) * 4, gk = kb + kg;
      float4 v = make_float4(0.f, 0.f, 0.f, 0.f);
      if (gk < SIG) v = *(const float4*)(Cmat + (size_t)(m0 + row) * SIG + gk);
      As[kg + 0][row] = v.x; As[kg + 1][row] = v.y;
      As[kg + 2][row] = v.z; As[kg + 3][row] = v.w;
    }
    {
      int row = tid >> 2, kg = (tid & 3) * 4, gk = kb + kg, wr = n0 + row;
      float4 v = make_float4(0.f, 0.f, 0.f, 0.f);
      if (gk < SIG && wr < SIG) v = *(const float4*)(W + (size_t)wr * SIG + gk);
      Ws[kg + 0][row] = v.x; Ws[kg + 1][row] = v.y;
      Ws[kg + 2][row] = v.z; Ws[kg + 3][row] = v.w;
    }
    __syncthreads();
#pragma unroll
    for (int k = 0; k < BK; ++k) {
      float af[8], wf[8];
      *(float4*)&af[0] = *(const float4*)&As[k][ty * 8];
      *(float4*)&af[4] = *(const float4*)&As[k][ty * 8 + 4];
      *(float4*)&wf[0] = *(const float4*)&Ws[k][tx * 8];
      *(float4*)&wf[4] = *(const float4*)&Ws[k][tx * 8 + 4];
#pragma unroll
      for (int i = 0; i < 8; ++i)
#pragma unroll
        for (int j = 0; j < 8; ++j) acc[i][j] = fmaf(af[i], wf[j], acc[i][j]);
    }
  }
#pragma unroll
  for (int i = 0; i < 8; ++i) {
    int m = m0 + ty * 8 + i;
    float* orow = out + (size_t)m * SIG;
#pragma unroll
    for (int jj = 0; jj < 8; jj += 4) {
      int col = n0 + tx * 8 + jj;
      if (col < SIG) {
        float4 r;
        r.x = tanhf(acc[i][jj + 0] + bias[col + 0]);
        r.y = tanhf(acc[i][jj + 1] + bias[col + 1]);
        r.z = tanhf(acc[i][jj + 2] + bias[col + 2]);
        r.w = tanhf(acc[i][jj + 3] + bias[col + 3]);
        *(float4*)(orow + col) = r;
      }
    }
  }
}

// ---------------- launch ----------------
extern "C" void kernel_launch(void* const* d_in, const int* in_sizes, int n_in,
                              void* d_out, int out_size, void* d_ws, size_t ws_size,
                              hipStream_t stream) {
  const float* batch = (const float*)d_in[0];
  const float* conv_w = (const float*)d_in[1];
  const float* conv_b = (const float*)d_in[2];
  const float* lin_w = (const float*)d_in[3];
  const float* lin_b = (const float*)d_in[4];
  float* out = (float*)d_out;

  const size_t plane_elems = (size_t)N_B * T_LEN * KP;        // 52,428,800
  const size_t wplane_elems = (size_t)896 * KP;               // 716,800
  const size_t P_elems = (size_t)N_B * N_SEG * SIG;           // 3,194,880
  const size_t bp_elems = (size_t)N_B * T_LEN * CH;           // 327,680
  const size_t need_big = 2 * plane_elems * sizeof(_Float16) +
                          2 * wplane_elems * sizeof(_Float16) +
                          P_elems * sizeof(float);

  if (ws_size >= need_big) {
    _Float16* c1 = (_Float16*)d_ws;
    _Float16* c2 = c1 + plane_elems;
    _Float16* w1 = c2 + plane_elems;
    _Float16* w2 = w1 + wplane_elems;
    float* P = (float*)(w2 + wplane_elems);

    wconv_kernel<<<dim3((896 * KP + 255) / 256), dim3(256), 0, stream>>>(
        lin_w, w1, w2);
    seg_kernel<<<dim3(N_SEG, N_B), dim3(320), 0, stream>>>(batch, conv_w, conv_b, P);
    prefix_kernel<<<dim3(N_B), dim3(640), 0, stream>>>(P);
    emit_kernel<<<dim3(N_SEG, N_B), dim3(320), 0, stream>>>(
        batch, conv_w, conv_b, P, c1, c2);
    gemm_mfma<<<dim3(7168), dim3(512), 0, stream>>>(c1, c2, w1, w2, lin_b, out);
  } else {
    float* b_path = (float*)d_ws;
    float* c_sig = (float*)d_ws + bp_elems;
    conv_kernel<<<dim3((N_B * T_LEN + 255) / 256), dim3(256), 0, stream>>>(
        batch, conv_w, conv_b, b_path);
    sig_kernel_fb<<<dim3(N_B), dim3(320), 0, stream>>>(b_path, c_sig);
    gemm_tanh_fb<<<dim3((N_B * T_LEN) / BM, (SIG + BN - 1) / BN), dim3(256), 0, stream>>>(
        c_sig, lin_w, lin_b, out);
  }
}

// Round 7
// 624.255 us; speedup vs baseline: 1.1663x; 1.1663x over previous
//
#include <hip/hip_runtime.h>
#include <math.h>

#define N_B 64
#define T_LEN 1024
#define IN_D 4
#define CH 5
#define SIG 780
#define KP 800           // padded K for f16 planes
#define SEG_LEN 16
#define N_SEG 64
// level offsets: L1:0, L2:5, L3:30, L4:155
#define SC_L1 1.0f
#define SC_L2 0.25f
#define SC_L3 0.0625f
#define SC_L4 0.015625f

typedef _Float16 f16x8 __attribute__((ext_vector_type(8)));
typedef float f32x4 __attribute__((ext_vector_type(4)));

typedef __attribute__((address_space(1))) const void* as1cp;
typedef __attribute__((address_space(3))) void* as3p;

#define VMCNT(n) asm volatile("s_waitcnt vmcnt(" #n ")" ::: "memory")

__device__ __forceinline__ float fast_tanh(float x) {
  float ax = fabsf(x);
  float e = __expf(-2.0f * ax);
  float r = (1.0f - e) * __builtin_amdgcn_rcpf(1.0f + e);
  return copysignf(r, x);
}

// ---------------- Kernel 1 (fallback only): time-aug + pointwise conv -------
__global__ __launch_bounds__(256) void conv_kernel(
    const float* __restrict__ batch,
    const float* __restrict__ conv_w,
    const float* __restrict__ conv_b,
    float* __restrict__ b_out) {
  int idx = blockIdx.x * blockDim.x + threadIdx.x;
  if (idx >= N_B * T_LEN) return;
  int t = idx & (T_LEN - 1);
  const float* a = batch + (size_t)idx * IN_D;
  float a0 = a[0], a1 = a[1], a2 = a[2], a3 = a[3];
  float tm = (float)(t + 1) / (float)T_LEN;
  float* o = b_out + (size_t)idx * CH;
#pragma unroll
  for (int j = 0; j < CH; ++j) {
    const float* w = conv_w + j * CH;
    float r = conv_b[j];
    r = fmaf(tm, w[4], r);
    r = fmaf(a3, w[3], r);
    r = fmaf(a2, w[2], r);
    r = fmaf(a1, w[1], r);
    r = fmaf(a0, w[0], r);
    o[j] = r;
  }
}

// ---------------- Signature phase A: per-segment signatures (conv fused) ----
// Ping-pong LDS state: 1 barrier per time-step.
__global__ __launch_bounds__(320) void seg_kernel(
    const float* __restrict__ batch,
    const float* __restrict__ conv_w,
    const float* __restrict__ conv_b,
    float* __restrict__ P) {
  int s = blockIdx.x;
  int n = blockIdx.y;
  int tid = threadIdx.x;

  __shared__ float S[2][SIG];
  __shared__ float bc[(SEG_LEN + 1) * CH];
  __shared__ float dsh[SEG_LEN][CH];

  for (int i = tid; i < SIG; i += 320) S[0][i] = 0.0f;
  if (tid < (SEG_LEN + 1) * CH) {
    int r = s * SEG_LEN - 1 + tid / CH, ch = tid % CH;
    float v = 0.0f;
    if (r >= 0) {
      const float* a = batch + ((size_t)n * T_LEN + r) * IN_D;
      const float* w = conv_w + ch * CH;
      v = conv_b[ch];
      v = fmaf(a[0], w[0], v);
      v = fmaf(a[1], w[1], v);
      v = fmaf(a[2], w[2], v);
      v = fmaf(a[3], w[3], v);
      v = fmaf((float)(r + 1) * (1.0f / T_LEN), w[4], v);
    }
    bc[tid] = v;
  }
  __syncthreads();
  if (tid < SEG_LEN * CH) {
    int j = tid / CH, ch = tid % CH;
    dsh[j][ch] = bc[(j + 1) * CH + ch] - bc[j * CH + ch];
  }

  const int x0 = tid;
  const int x1 = tid + 320;
  const bool has1 = (tid < 305);
  const int a0i = x0 / 125, b0i = (x0 / 25) % 5, c0i = (x0 / 5) % 5, d0i = x0 % 5;
  const int a1i = x1 / 125, b1i = (x1 / 25) % 5, c1i = (x1 / 5) % 5, d1i = x1 % 5;
  const int s2_0 = x0 / 25, s3_0 = x0 / 5;
  const int s2_1 = x1 / 25, s3_1 = x1 / 5;
  const bool hasL3 = (tid < 125);
  const int ya = tid / 25, yb = (tid / 5) % 5, yc = tid % 5;
  const bool hasL2 = (tid < 25);
  const int za = tid / 5, zb = tid % 5;
  const bool hasL1 = (tid < CH);
  __syncthreads();

  int c = 0;
  for (int j = 0; j < SEG_LEN; ++j) {
    const float* Sc = S[c];
    float* Sn = S[c ^ 1];
    float n4_0, n4_1 = 0.0f, n3 = 0.0f, n2 = 0.0f, n1 = 0.0f;
    {
      float tH = fmaf(0.25f, dsh[j][a0i], Sc[a0i]);
      tH = fmaf((1.0f / 3.0f) * dsh[j][b0i], tH, Sc[5 + s2_0]);
      tH = fmaf(0.5f * dsh[j][c0i], tH, Sc[30 + s3_0]);
      n4_0 = fmaf(dsh[j][d0i], tH, Sc[155 + x0]);
    }
    if (has1) {
      float tH = fmaf(0.25f, dsh[j][a1i], Sc[a1i]);
      tH = fmaf((1.0f / 3.0f) * dsh[j][b1i], tH, Sc[5 + s2_1]);
      tH = fmaf(0.5f * dsh[j][c1i], tH, Sc[30 + s3_1]);
      n4_1 = fmaf(dsh[j][d1i], tH, Sc[155 + x1]);
    }
    if (hasL3) {
      float tH = fmaf((1.0f / 3.0f), dsh[j][ya], Sc[ya]);
      tH = fmaf(0.5f * dsh[j][yb], tH, Sc[5 + ya * 5 + yb]);
      n3 = fmaf(dsh[j][yc], tH, Sc[30 + tid]);
    }
    if (hasL2) {
      float tH = fmaf(0.5f, dsh[j][za], Sc[za]);
      n2 = fmaf(dsh[j][zb], tH, Sc[5 + tid]);
    }
    if (hasL1) n1 = Sc[tid] + dsh[j][tid];
    Sn[155 + x0] = n4_0;
    if (has1) Sn[155 + x1] = n4_1;
    if (hasL3) Sn[30 + tid] = n3;
    if (hasL2) Sn[5 + tid] = n2;
    if (hasL1) Sn[tid] = n1;
    __syncthreads();
    c ^= 1;
  }

  float* Pr = P + ((size_t)n * N_SEG + s) * SIG;
  for (int i = tid; i < SIG; i += 320) Pr[i] = S[c][i];
}

// ---------------- Signature phase B: sequential prefix (ping-pong, 1 bar) ---
__global__ __launch_bounds__(640) void prefix_kernel(float* __restrict__ P) {
  int n = blockIdx.x;
  int tid = threadIdx.x;
  __shared__ float A[2][SIG];
  __shared__ float Bs[SIG];

  float* Pn = P + (size_t)n * N_SEG * SIG;
  for (int i = tid; i < SIG; i += 640) A[0][i] = Pn[i];
  int i0 = tid, i1 = tid + 640;
  float r0 = 0.f, r1 = 0.f;
  if (i0 < SIG) r0 = Pn[SIG + i0];
  if (i1 < SIG) r1 = Pn[SIG + i1];

  const int e4 = tid;
  const int q4a = e4 / 125, r125 = e4 % 125, r25 = e4 % 25, r5 = e4 % 5;
  const int e4d5 = e4 / 5, e4d25 = e4 / 25;
  const int e3 = tid;
  const int e3a = e3 / 25, e3r25 = e3 % 25, e3r5 = e3 % 5, e3d5 = e3 / 5;
  const int e2 = tid - 125;
  const int e1 = tid - 150;

  int c = 0;
  for (int s = 1; s < N_SEG; ++s) {
    if (i0 < SIG) Bs[i0] = r0;
    if (i1 < SIG) Bs[i1] = r1;
    __syncthreads();   // Bs ready; prev iter's A[c] writes visible
    if (s + 1 < N_SEG) {
      const float* Pnx = Pn + (size_t)(s + 1) * SIG;
      if (i0 < SIG) r0 = Pnx[i0];
      if (i1 < SIG) r1 = Pnx[i1];
    }
    const float* Ac = A[c];
    float* An = A[c ^ 1];
    float* Po = Pn + (size_t)s * SIG;
    if (tid < 625) {
      float v4 = Ac[155 + e4] + Bs[155 + e4];
      v4 = fmaf(Ac[30 + e4d5], Bs[r5], v4);
      v4 = fmaf(Ac[5 + e4d25], Bs[5 + r25], v4);
      v4 = fmaf(Ac[q4a], Bs[30 + r125], v4);
      An[155 + e4] = v4; Po[155 + e4] = v4;
    }
    if (tid < 125) {
      float v3 = Ac[30 + e3] + Bs[30 + e3];
      v3 = fmaf(Ac[5 + e3d5], Bs[e3r5], v3);
      v3 = fmaf(Ac[e3a], Bs[5 + e3r25], v3);
      An[30 + e3] = v3; Po[30 + e3] = v3;
    } else if (tid < 150) {
      float v2 = Ac[5 + e2] + Bs[5 + e2];
      v2 = fmaf(Ac[e2 / 5], Bs[e2 % 5], v2);
      An[5 + e2] = v2; Po[5 + e2] = v2;
    } else if (tid < 155) {
      float v1 = Ac[e1] + Bs[e1];
      An[e1] = v1; Po[e1] = v1;
    }
    c ^= 1;
  }
}

// ---------------- Signature phase C: stream + emit f16 planes ----------------
// Ping-pong S and row buffers: 1 barrier per time-step; store of row t-1
// overlaps iteration t's compute.
__global__ __launch_bounds__(320) void emit_kernel(
    const float* __restrict__ batch,
    const float* __restrict__ conv_w,
    const float* __restrict__ conv_b,
    const float* __restrict__ P,
    _Float16* __restrict__ c1,
    _Float16* __restrict__ c2) {
  int s = blockIdx.x;
  int n = blockIdx.y;
  int tid = threadIdx.x;

  __shared__ float S[2][SIG];
  __shared__ float bc[(SEG_LEN + 1) * CH];
  __shared__ float dsh[SEG_LEN][CH];
  __shared__ __align__(16) _Float16 row1[2][KP];
  __shared__ __align__(16) _Float16 row2[2][KP];

  if (s == 0) {
    for (int i = tid; i < SIG; i += 320) S[0][i] = 0.0f;
  } else {
    const float* Pr = P + ((size_t)n * N_SEG + (s - 1)) * SIG;
    for (int i = tid; i < SIG; i += 320) S[0][i] = Pr[i];
  }
  if (tid < (SEG_LEN + 1) * CH) {
    int r = s * SEG_LEN - 1 + tid / CH, ch = tid % CH;
    float v = 0.0f;
    if (r >= 0) {
      const float* a = batch + ((size_t)n * T_LEN + r) * IN_D;
      const float* w = conv_w + ch * CH;
      v = conv_b[ch];
      v = fmaf(a[0], w[0], v);
      v = fmaf(a[1], w[1], v);
      v = fmaf(a[2], w[2], v);
      v = fmaf(a[3], w[3], v);
      v = fmaf((float)(r + 1) * (1.0f / T_LEN), w[4], v);
    }
    bc[tid] = v;
  }
  if (tid < KP - SIG) {  // zero the pad tails once (both ping-pong buffers)
    row1[0][SIG + tid] = (_Float16)0.0f;
    row1[1][SIG + tid] = (_Float16)0.0f;
    row2[0][SIG + tid] = (_Float16)0.0f;
    row2[1][SIG + tid] = (_Float16)0.0f;
  }
  __syncthreads();
  if (tid < SEG_LEN * CH) {
    int j = tid / CH, ch = tid % CH;
    dsh[j][ch] = bc[(j + 1) * CH + ch] - bc[j * CH + ch];
  }

  const int x0 = tid;
  const int x1 = tid + 320;
  const bool has1 = (tid < 305);
  const int a0i = x0 / 125, b0i = (x0 / 25) % 5, c0i = (x0 / 5) % 5, d0i = x0 % 5;
  const int a1i = x1 / 125, b1i = (x1 / 25) % 5, c1i = (x1 / 5) % 5, d1i = x1 % 5;
  const int s2_0 = x0 / 25, s3_0 = x0 / 5;
  const int s2_1 = x1 / 25, s3_1 = x1 / 5;
  const bool hasL3 = (tid < 125);
  const int ya = tid / 25, yb = (tid / 5) % 5, yc = tid % 5;
  const bool hasL2 = (tid < 25);
  const int za = tid / 5, zb = tid % 5;
  const bool hasL1 = (tid < CH);
  __syncthreads();

  int c = 0;
  for (int j = 0; j < SEG_LEN; ++j) {
    int t = s * SEG_LEN + j;
    const float* Sc = S[c];
    float* Sn = S[c ^ 1];
    float n4_0, n4_1 = 0.0f, n3 = 0.0f, n2 = 0.0f, n1 = 0.0f;
    {
      float tH = fmaf(0.25f, dsh[j][a0i], Sc[a0i]);
      tH = fmaf((1.0f / 3.0f) * dsh[j][b0i], tH, Sc[5 + s2_0]);
      tH = fmaf(0.5f * dsh[j][c0i], tH, Sc[30 + s3_0]);
      n4_0 = fmaf(dsh[j][d0i], tH, Sc[155 + x0]);
    }
    if (has1) {
      float tH = fmaf(0.25f, dsh[j][a1i], Sc[a1i]);
      tH = fmaf((1.0f / 3.0f) * dsh[j][b1i], tH, Sc[5 + s2_1]);
      tH = fmaf(0.5f * dsh[j][c1i], tH, Sc[30 + s3_1]);
      n4_1 = fmaf(dsh[j][d1i], tH, Sc[155 + x1]);
    }
    if (hasL3) {
      float tH = fmaf((1.0f / 3.0f), dsh[j][ya], Sc[ya]);
      tH = fmaf(0.5f * dsh[j][yb], tH, Sc[5 + ya * 5 + yb]);
      n3 = fmaf(dsh[j][yc], tH, Sc[30 + tid]);
    }
    if (hasL2) {
      float tH = fmaf(0.5f, dsh[j][za], Sc[za]);
      n2 = fmaf(dsh[j][zb], tH, Sc[5 + tid]);
    }
    if (hasL1) n1 = Sc[tid] + dsh[j][tid];

    // overlapped store of the PREVIOUS row (completed at last barrier)
    if (j > 0) {
      size_t base = ((size_t)n * T_LEN + (t - 1)) * KP;
      if (tid < 100) {
        *(float4*)(c1 + base + tid * 8) = *(const float4*)&row1[c][tid * 8];
      } else if (tid < 200) {
        int cc = tid - 100;
        *(float4*)(c2 + base + cc * 8) = *(const float4*)&row2[c][cc * 8];
      }
    }

    // commit state + build scaled f16 row into the OTHER buffers
    Sn[155 + x0] = n4_0;
    if (has1) Sn[155 + x1] = n4_1;
    if (hasL3) Sn[30 + tid] = n3;
    if (hasL2) Sn[5 + tid] = n2;
    if (hasL1) Sn[tid] = n1;

    float z = (t == 0) ? 0.0f : 1.0f;
    {
      float v = n4_0 * SC_L4 * z;
      _Float16 h = (_Float16)v;
      row1[c ^ 1][155 + x0] = h; row2[c ^ 1][155 + x0] = (_Float16)(v - (float)h);
    }
    if (has1) {
      float v = n4_1 * SC_L4 * z;
      _Float16 h = (_Float16)v;
      row1[c ^ 1][155 + x1] = h; row2[c ^ 1][155 + x1] = (_Float16)(v - (float)h);
    }
    if (hasL3) {
      float v = n3 * SC_L3 * z;
      _Float16 h = (_Float16)v;
      row1[c ^ 1][30 + tid] = h; row2[c ^ 1][30 + tid] = (_Float16)(v - (float)h);
    }
    if (hasL2) {
      float v = n2 * SC_L2 * z;
      _Float16 h = (_Float16)v;
      row1[c ^ 1][5 + tid] = h; row2[c ^ 1][5 + tid] = (_Float16)(v - (float)h);
    }
    if (hasL1) {
      float v = n1 * SC_L1 * z;
      _Float16 h = (_Float16)v;
      row1[c ^ 1][tid] = h; row2[c ^ 1][tid] = (_Float16)(v - (float)h);
    }
    __syncthreads();
    c ^= 1;
  }
  // final row (t = s*SEG_LEN + 15)
  {
    size_t base = ((size_t)n * T_LEN + (s * SEG_LEN + SEG_LEN - 1)) * KP;
    if (tid < 100) {
      *(float4*)(c1 + base + tid * 8) = *(const float4*)&row1[c][tid * 8];
    } else if (tid < 200) {
      int cc = tid - 100;
      *(float4*)(c2 + base + cc * 8) = *(const float4*)&row2[c][cc * 8];
    }
  }
}

// ---------------- W plane conversion (scaled, padded to 896x800) -------------
__global__ __launch_bounds__(256) void wconv_kernel(
    const float* __restrict__ W,
    _Float16* __restrict__ w1,
    _Float16* __restrict__ w2) {
  int idx = blockIdx.x * blockDim.x + threadIdx.x;
  if (idx >= 896 * KP) return;
  int nn = idx / KP, k = idx % KP;
  float v = 0.0f;
  if (nn < SIG && k < SIG) {
    float sc = (k < 5) ? 1.0f : (k < 30) ? 4.0f : (k < 155) ? 16.0f : 64.0f;
    v = W[(size_t)nn * SIG + k] * sc;
  }
  _Float16 h = (_Float16)v;
  w1[idx] = h;
  w2[idx] = (_Float16)(v - (float)h);
}

// ---------------- MFMA GEMM: out = tanh((c1+c2)*(w1+w2)^T + b) ---------------
// Round 7: R1 structure (256x128, 8 waves 64x64, 3 LDS bufs, vmcnt(6),
// prefetch depth 2) with the TWO MID-PHASE BARRIERS REMOVED. Those barriers
// forced all 8 waves into lockstep all-read -> all-MFMA bursts (LDS pipe
// ~2090 cyc then MFMA pipe ~1863 cyc, serialized = the measured 5143
// cyc/K-step). They are not needed for correctness: reads come from buf[cur]
// (published at the top barrier), stages write buf[cur+2] (untouched for two
// more top barriers), vmcnt is per-wave. Without them waves drift within the
// K-step, so one wave's ds_reads overlap another's MFMAs; the top barrier
// re-syncs each K-step. Reads ordered B0,A0..A3,B1..B3 with tn-major MFMA so
// the first 12 MFMAs need only 4 reads.
__global__ __launch_bounds__(512, 2) void gemm_mfma(
    const _Float16* __restrict__ A1p, const _Float16* __restrict__ A2p,
    const _Float16* __restrict__ B1p, const _Float16* __restrict__ B2p,
    const float* __restrict__ bias, float* __restrict__ out) {
  __shared__ _Float16 Al[3][2][256 * 32];  // [buf][plane] : 96 KB
  __shared__ _Float16 Bl[3][2][128 * 32];  // [buf][plane] : 48 KB

  int tid = threadIdx.x;
  int lane = tid & 63, wid = tid >> 6;
  int wm = wid >> 1, wn = wid & 1;

  // XCD-bijective swizzle: the 7 n-siblings of each m-tile share one XCD.
  int b = blockIdx.x;
  int xcd = b & 7, sidx = b >> 3;
  int mt = (sidx / 7) * 8 + xcd;
  int nt = sidx % 7;
  int m0 = mt * 256;
  int n0 = nt * 128;

  f32x4 acc[4][4];
#pragma unroll
  for (int i = 0; i < 4; ++i)
#pragma unroll
    for (int j = 0; j < 4; ++j) acc[i][j] = (f32x4){0.f, 0.f, 0.f, 0.f};

  int sr = lane >> 2, scn = lane & 3;
  int swst = (sr ^ (sr >> 2)) & 3;
  int qg = scn ^ swst;          // pre-swizzled global chunk (LDS stays linear)
  int fr = lane & 15, fq = lane >> 4;
  int swf = (fr ^ (fr >> 2)) & 3;
  int fchunk = fq ^ swf;        // matching read-side swizzle

  auto stageA = [&](int kb, int buf, int i) {
    int k0 = kb * 32;
    int linear = wid * 4 + i;          // 0..31
    int plane = linear >> 4, grp = linear & 15;
    size_t g = (size_t)(m0 + grp * 16 + sr) * KP + k0 + qg * 8;
    const _Float16* src = (plane ? A2p : A1p) + g;
    __builtin_amdgcn_global_load_lds((as1cp)src, (as3p)(&Al[buf][plane][grp * 512]), 16, 0, 0);
  };
  auto stageB = [&](int kb, int buf, int i) {
    int k0 = kb * 32;
    int linear = wid * 2 + i;          // 0..15
    int plane = linear >> 3, grp = linear & 7;
    size_t g = (size_t)(n0 + grp * 16 + sr) * KP + k0 + qg * 8;
    const _Float16* src = (plane ? B2p : B1p) + g;
    __builtin_amdgcn_global_load_lds((as1cp)src, (as3p)(&Bl[buf][plane][grp * 512]), 16, 0, 0);
  };

  // prologue: tiles 0 and 1 in flight (12 loads/thread)
#pragma unroll
  for (int i = 0; i < 4; ++i) stageA(0, 0, i);
#pragma unroll
  for (int i = 0; i < 2; ++i) stageB(0, 0, i);
#pragma unroll
  for (int i = 0; i < 4; ++i) stageA(1, 1, i);
#pragma unroll
  for (int i = 0; i < 2; ++i) stageB(1, 1, i);

  int cur = 0;
#pragma unroll 1
  for (int kb = 0; kb < 25; ++kb) {
    int nx = cur + 2; if (nx >= 3) nx -= 3;
    bool pf = (kb + 2 < 25);
    // counted wait: tile kb done, tile kb+1's 6 loads stay in flight
    if (kb < 24) { VMCNT(6); } else { VMCNT(0); }
    __builtin_amdgcn_s_barrier();
    __builtin_amdgcn_sched_barrier(0);
    f16x8 a1f[4], a2f[4], b1f[4], b2f[4];
    // read order: B0, A0..A3, B1..B3 (first 12 MFMAs enabled after 4 reads)
    {
      int off = (wn * 64 + 0 * 16 + fr) * 32 + fchunk * 8;
      b1f[0] = *(const f16x8*)&Bl[cur][0][off];
      b2f[0] = *(const f16x8*)&Bl[cur][1][off];
    }
#pragma unroll
    for (int tm = 0; tm < 4; ++tm) {
      int off = (wm * 64 + tm * 16 + fr) * 32 + fchunk * 8;
      a1f[tm] = *(const f16x8*)&Al[cur][0][off];
      a2f[tm] = *(const f16x8*)&Al[cur][1][off];
    }
#pragma unroll
    for (int tn = 1; tn < 4; ++tn) {
      int off = (wn * 64 + tn * 16 + fr) * 32 + fchunk * 8;
      b1f[tn] = *(const f16x8*)&Bl[cur][0][off];
      b2f[tn] = *(const f16x8*)&Bl[cur][1][off];
    }
    if (pf) {  // issue next-next tile loads; they ride across barriers
      stageA(kb + 2, nx, 0); stageA(kb + 2, nx, 1);
      stageA(kb + 2, nx, 2); stageA(kb + 2, nx, 3);
      stageB(kb + 2, nx, 0); stageB(kb + 2, nx, 1);
    }
    // NO mid barrier: waves free-run; counted lgkmcnt gates each MFMA on its
    // own operands, so reads of later tn overlap MFMAs of earlier tn, and
    // drifted waves overlap reads with other waves' MFMAs.
    __builtin_amdgcn_s_setprio(1);
#pragma unroll
    for (int tn = 0; tn < 4; ++tn) {
#pragma unroll
      for (int tm = 0; tm < 4; ++tm) {
        acc[tm][tn] = __builtin_amdgcn_mfma_f32_16x16x32_f16(a1f[tm], b1f[tn], acc[tm][tn], 0, 0, 0);
        acc[tm][tn] = __builtin_amdgcn_mfma_f32_16x16x32_f16(a1f[tm], b2f[tn], acc[tm][tn], 0, 0, 0);
        acc[tm][tn] = __builtin_amdgcn_mfma_f32_16x16x32_f16(a2f[tm], b1f[tn], acc[tm][tn], 0, 0, 0);
      }
    }
    __builtin_amdgcn_s_setprio(0);
    cur = cur + 1; if (cur >= 3) cur -= 3;
  }
  __syncthreads();  // all frag reads done; LDS reusable for epilogue

  // epilogue: bias + fast tanh, per-wave LDS transpose, float4 stores
  float* ep = (float*)(&Al[0][0][0]) + wid * 2112;  // 32x66 f32 per wave

  float bv[4];
#pragma unroll
  for (int tn = 0; tn < 4; ++tn) {
    int nn = n0 + wn * 64 + tn * 16 + fr;
    bv[tn] = (nn < SIG) ? bias[nn] : 0.0f;
  }
#pragma unroll
  for (int h = 0; h < 2; ++h) {
#pragma unroll
    for (int tm2 = 0; tm2 < 2; ++tm2) {
      int tm = h * 2 + tm2;
#pragma unroll
      for (int tn = 0; tn < 4; ++tn) {
#pragma unroll
        for (int r = 0; r < 4; ++r) {
          int lr = tm2 * 16 + fq * 4 + r;  // 0..31
          int lc = tn * 16 + fr;           // 0..63
          ep[lr * 66 + lc] = fast_tanh(acc[tm][tn][r] + bv[tn]);
        }
      }
    }
    // wave-synchronous readout: 32 rows x 64 cols, float4 per 4 cols
#pragma unroll
    for (int p = 0; p < 2; ++p) {
      int lr = lane & 31;
      int ck = (lane >> 5) * 2 + p;  // 0..3 (16-col chunk)
      int gm = m0 + wm * 64 + h * 32 + lr;
      int gc0 = n0 + wn * 64 + ck * 16;
#pragma unroll
      for (int q = 0; q < 4; ++q) {
        int col = gc0 + q * 4;
        if (col + 3 < SIG) {
          *(float4*)(out + (size_t)gm * SIG + col) =
              *(const float4*)&ep[lr * 66 + ck * 16 + q * 4];
        } else if (col < SIG) {
#pragma unroll
          for (int e = 0; e < 4; ++e) {
            int c2 = col + e;
            if (c2 < SIG) out[(size_t)gm * SIG + c2] = ep[lr * 66 + ck * 16 + q * 4 + e];
          }
        }
      }
    }
  }
}

// ================= FALLBACK PATH (round-1, fp32) =============================
__global__ __launch_bounds__(320) void sig_kernel_fb(
    const float* __restrict__ b_in, float* __restrict__ c_out) {
  int n = blockIdx.x;
  int tid = threadIdx.x;
  __shared__ float S[SIG];
  __shared__ float bc[64 * CH];
  __shared__ float dsh[CH];
  __shared__ float pb[CH];
  for (int i = tid; i < SIG; i += 320) S[i] = 0.0f;
  if (tid < CH) pb[tid] = 0.0f;
  const float* bn = b_in + (size_t)n * T_LEN * CH;
  float* cn = c_out + (size_t)n * T_LEN * SIG;
  const int x0 = tid, x1 = tid + 320;
  const bool has1 = (tid < 305);
  const int a0i = x0 / 125, b0i = (x0 / 25) % 5, c0i = (x0 / 5) % 5, d0i = x0 % 5;
  const int a1i = x1 / 125, b1i = (x1 / 25) % 5, c1i = (x1 / 5) % 5, d1i = x1 % 5;
  const int s2_0 = x0 / 25, s3_0 = x0 / 5, s2_1 = x1 / 25, s3_1 = x1 / 5;
  const bool hasL3 = (tid < 125);
  const int ya = tid / 25, yb = (tid / 5) % 5, yc = tid % 5;
  const bool hasL2 = (tid < 25);
  const int za = tid / 5, zb = tid % 5;
  const bool hasL1 = (tid < CH);
  for (int t = 0; t < T_LEN; ++t) {
    if ((t & 63) == 0) {
      __syncthreads();
      bc[tid] = bn[t * CH + tid];
      __syncthreads();
    }
    if (tid < CH) {
      float cur = bc[(t & 63) * CH + tid];
      dsh[tid] = cur - pb[tid];
      pb[tid] = cur;
    }
    __syncthreads();
    float n4_0, n4_1 = 0.0f, n3 = 0.0f, n2 = 0.0f, n1 = 0.0f;
    {
      float tH = fmaf(0.25f, dsh[a0i], S[a0i]);
      tH = fmaf((1.0f / 3.0f) * dsh[b0i], tH, S[5 + s2_0]);
      tH = fmaf(0.5f * dsh[c0i], tH, S[30 + s3_0]);
      n4_0 = fmaf(dsh[d0i], tH, S[155 + x0]);
    }
    if (has1) {
      float tH = fmaf(0.25f, dsh[a1i], S[a1i]);
      tH = fmaf((1.0f / 3.0f) * dsh[b1i], tH, S[5 + s2_1]);
      tH = fmaf(0.5f * dsh[c1i], tH, S[30 + s3_1]);
      n4_1 = fmaf(dsh[d1i], tH, S[155 + x1]);
    }
    if (hasL3) {
      float tH = fmaf((1.0f / 3.0f), dsh[ya], S[ya]);
      tH = fmaf(0.5f * dsh[yb], tH, S[5 + ya * 5 + yb]);
      n3 = fmaf(dsh[yc], tH, S[30 + tid]);
    }
    if (hasL2) {
      float tH = fmaf(0.5f, dsh[za], S[za]);
      n2 = fmaf(dsh[zb], tH, S[5 + tid]);
    }
    if (hasL1) n1 = S[tid] + dsh[tid];
    __syncthreads();
    S[155 + x0] = n4_0;
    if (has1) S[155 + x1] = n4_1;
    if (hasL3) S[30 + tid] = n3;
    if (hasL2) S[5 + tid] = n2;
    if (hasL1) S[tid] = n1;
    float* crow = cn + (size_t)t * SIG;
    float z = (t == 0) ? 0.0f : 1.0f;
    crow[155 + x0] = n4_0 * z;
    if (has1) crow[155 + x1] = n4_1 * z;
    if (hasL3) crow[30 + tid] = n3 * z;
    if (hasL2) crow[5 + tid] = n2 * z;
    if (hasL1) crow[tid] = n1 * z;
    __syncthreads();
  }
}

#define BM 256
#define BN 64
#define BK 16
__global__ __launch_bounds__(256) void gemm_tanh_fb(
    const float* __restrict__ Cmat, const float* __restrict__ W,
    const float* __restrict__ bias, float* __restrict__ out) {
  __shared__ float As[BK][BM + 4];
  __shared__ float Ws[BK][BN + 4];
  int tid = threadIdx.x;
  int tx = tid & 7, ty = tid >> 3;
  int m0 = blockIdx.x * BM, n0 = blockIdx.y * BN;
  float acc[8][8];
#pragma unroll
  for (int i = 0; i < 8; ++i)
#pragma unroll
    for (int j = 0; j < 8; ++j) acc[i][j] = 0.0f;
  for (int kb = 0; kb < SIG; kb += BK) {
    __syncthreads();
#pragma unroll
    for (int p = 0; p < 4; ++p) {
      int id = tid + p * 256;
      int row = id >> 2, kg = (id & 3) * 4, gk = kb + kg;
      float4 v = make_float4(0.f, 0.f, 0.f, 0.f);
      if (gk < SIG) v = *(const float4*)(Cmat + (size_t)(m0 + row) * SIG + gk);
      As[kg + 0][row] = v.x; As[kg + 1][row] = v.y;
      As[kg + 2][row] = v.z; As[kg + 3][row] = v.w;
    }
    {
      int row = tid >> 2, kg = (tid & 3) * 4, gk = kb + kg, wr = n0 + row;
      float4 v = make_float4(0.f, 0.f, 0.f, 0.f);
      if (gk < SIG && wr < SIG) v = *(const float4*)(W + (size_t)wr * SIG + gk);
      Ws[kg + 0][row] = v.x; Ws[kg + 1][row] = v.y;
      Ws[kg + 2][row] = v.z; Ws[kg + 3][row] = v.w;
    }
    __syncthreads();
#pragma unroll
    for (int k = 0; k < BK; ++k) {
      float af[8], wf[8];
      *(float4*)&af[0] = *(const float4*)&As[k][ty * 8];
      *(float4*)&af[4] = *(const float4*)&As[k][ty * 8 + 4];
      *(float4*)&wf[0] = *(const float4*)&Ws[k][tx * 8];
      *(float4*)&wf[4] = *(const float4*)&Ws[k][tx * 8 + 4];
#pragma unroll
      for (int i = 0; i < 8; ++i)
#pragma unroll
        for (int j = 0; j < 8; ++j) acc[i][j] = fmaf(af[i], wf[j], acc[i][j]);
    }
  }
#pragma unroll
  for (int i = 0; i < 8; ++i) {
    int m = m0 + ty * 8 + i;
    float* orow = out + (size_t)m * SIG;
#pragma unroll
    for (int jj = 0; jj < 8; jj += 4) {
      int col = n0 + tx * 8 + jj;
      if (col < SIG) {
        float4 r;
        r.x = tanhf(acc[i][jj + 0] + bias[col + 0]);
        r.y = tanhf(acc[i][jj + 1] + bias[col + 1]);
        r.z = tanhf(acc[i][jj + 2] + bias[col + 2]);
        r.w = tanhf(acc[i][jj + 3] + bias[col + 3]);
        *(float4*)(orow + col) = r;
      }
    }
  }
}

// ---------------- launch ----------------
extern "C" void kernel_launch(void* const* d_in, const int* in_sizes, int n_in,
                              void* d_out, int out_size, void* d_ws, size_t ws_size,
                              hipStream_t stream) {
  const float* batch = (const float*)d_in[0];
  const float* conv_w = (const float*)d_in[1];
  const float* conv_b = (const float*)d_in[2];
  const float* lin_w = (const float*)d_in[3];
  const float* lin_b = (const float*)d_in[4];
  float* out = (float*)d_out;

  const size_t plane_elems = (size_t)N_B * T_LEN * KP;        // 52,428,800
  const size_t wplane_elems = (size_t)896 * KP;               // 716,800
  const size_t P_elems = (size_t)N_B * N_SEG * SIG;           // 3,194,880
  const size_t bp_elems = (size_t)N_B * T_LEN * CH;           // 327,680
  const size_t need_big = 2 * plane_elems * sizeof(_Float16) +
                          2 * wplane_elems * sizeof(_Float16) +
                          P_elems * sizeof(float);

  if (ws_size >= need_big) {
    _Float16* c1 = (_Float16*)d_ws;
    _Float16* c2 = c1 + plane_elems;
    _Float16* w1 = c2 + plane_elems;
    _Float16* w2 = w1 + wplane_elems;
    float* P = (float*)(w2 + wplane_elems);

    wconv_kernel<<<dim3((896 * KP + 255) / 256), dim3(256), 0, stream>>>(
        lin_w, w1, w2);
    seg_kernel<<<dim3(N_SEG, N_B), dim3(320), 0, stream>>>(batch, conv_w, conv_b, P);
    prefix_kernel<<<dim3(N_B), dim3(640), 0, stream>>>(P);
    emit_kernel<<<dim3(N_SEG, N_B), dim3(320), 0, stream>>>(
        batch, conv_w, conv_b, P, c1, c2);
    gemm_mfma<<<dim3(1792), dim3(512), 0, stream>>>(c1, c2, w1, w2, lin_b, out);
  } else {
    float* b_path = (float*)d_ws;
    float* c_sig = (float*)d_ws + bp_elems;
    conv_kernel<<<dim3((N_B * T_LEN + 255) / 256), dim3(256), 0, stream>>>(
        batch, conv_w, conv_b, b_path);
    sig_kernel_fb<<<dim3(N_B), dim3(320), 0, stream>>>(b_path, c_sig);
    gemm_tanh_fb<<<dim3((N_B * T_LEN) / BM, (SIG + BN - 1) / BN), dim3(256), 0, stream>>>(
        c_sig, lin_w, lin_b, out);
  }
}

// Round 8
// 623.206 us; speedup vs baseline: 1.1683x; 1.0017x over previous
//
#include <hip/hip_runtime.h>
#include <math.h>

#define N_B 64
#define T_LEN 1024
#define IN_D 4
#define CH 5
#define SIG 780
#define KP 800           // padded K for f16 planes
#define SEG_LEN 16
#define N_SEG 64
// level offsets: L1:0, L2:5, L3:30, L4:155
#define SC_L1 1.0f
#define SC_L2 0.25f
#define SC_L3 0.0625f
#define SC_L4 0.015625f

typedef _Float16 f16x8 __attribute__((ext_vector_type(8)));
typedef float f32x4 __attribute__((ext_vector_type(4)));

typedef __attribute__((address_space(1))) const void* as1cp;
typedef __attribute__((address_space(3))) void* as3p;

#define VMCNT(n) asm volatile("s_waitcnt vmcnt(" #n ")" ::: "memory")

__device__ __forceinline__ float fast_tanh(float x) {
  float ax = fabsf(x);
  float e = __expf(-2.0f * ax);
  float r = (1.0f - e) * __builtin_amdgcn_rcpf(1.0f + e);
  return copysignf(r, x);
}

// ---------------- Kernel 1 (fallback only): time-aug + pointwise conv -------
__global__ __launch_bounds__(256) void conv_kernel(
    const float* __restrict__ batch,
    const float* __restrict__ conv_w,
    const float* __restrict__ conv_b,
    float* __restrict__ b_out) {
  int idx = blockIdx.x * blockDim.x + threadIdx.x;
  if (idx >= N_B * T_LEN) return;
  int t = idx & (T_LEN - 1);
  const float* a = batch + (size_t)idx * IN_D;
  float a0 = a[0], a1 = a[1], a2 = a[2], a3 = a[3];
  float tm = (float)(t + 1) / (float)T_LEN;
  float* o = b_out + (size_t)idx * CH;
#pragma unroll
  for (int j = 0; j < CH; ++j) {
    const float* w = conv_w + j * CH;
    float r = conv_b[j];
    r = fmaf(tm, w[4], r);
    r = fmaf(a3, w[3], r);
    r = fmaf(a2, w[2], r);
    r = fmaf(a1, w[1], r);
    r = fmaf(a0, w[0], r);
    o[j] = r;
  }
}

// ---------------- Signature phase A: per-segment signatures (conv fused) ----
// Ping-pong LDS state: 1 barrier per time-step.
__global__ __launch_bounds__(320) void seg_kernel(
    const float* __restrict__ batch,
    const float* __restrict__ conv_w,
    const float* __restrict__ conv_b,
    float* __restrict__ P) {
  int s = blockIdx.x;
  int n = blockIdx.y;
  int tid = threadIdx.x;

  __shared__ float S[2][SIG];
  __shared__ float bc[(SEG_LEN + 1) * CH];
  __shared__ float dsh[SEG_LEN][CH];

  for (int i = tid; i < SIG; i += 320) S[0][i] = 0.0f;
  if (tid < (SEG_LEN + 1) * CH) {
    int r = s * SEG_LEN - 1 + tid / CH, ch = tid % CH;
    float v = 0.0f;
    if (r >= 0) {
      const float* a = batch + ((size_t)n * T_LEN + r) * IN_D;
      const float* w = conv_w + ch * CH;
      v = conv_b[ch];
      v = fmaf(a[0], w[0], v);
      v = fmaf(a[1], w[1], v);
      v = fmaf(a[2], w[2], v);
      v = fmaf(a[3], w[3], v);
      v = fmaf((float)(r + 1) * (1.0f / T_LEN), w[4], v);
    }
    bc[tid] = v;
  }
  __syncthreads();
  if (tid < SEG_LEN * CH) {
    int j = tid / CH, ch = tid % CH;
    dsh[j][ch] = bc[(j + 1) * CH + ch] - bc[j * CH + ch];
  }

  const int x0 = tid;
  const int x1 = tid + 320;
  const bool has1 = (tid < 305);
  const int a0i = x0 / 125, b0i = (x0 / 25) % 5, c0i = (x0 / 5) % 5, d0i = x0 % 5;
  const int a1i = x1 / 125, b1i = (x1 / 25) % 5, c1i = (x1 / 5) % 5, d1i = x1 % 5;
  const int s2_0 = x0 / 25, s3_0 = x0 / 5;
  const int s2_1 = x1 / 25, s3_1 = x1 / 5;
  const bool hasL3 = (tid < 125);
  const int ya = tid / 25, yb = (tid / 5) % 5, yc = tid % 5;
  const bool hasL2 = (tid < 25);
  const int za = tid / 5, zb = tid % 5;
  const bool hasL1 = (tid < CH);
  __syncthreads();

  int c = 0;
  for (int j = 0; j < SEG_LEN; ++j) {
    const float* Sc = S[c];
    float* Sn = S[c ^ 1];
    float n4_0, n4_1 = 0.0f, n3 = 0.0f, n2 = 0.0f, n1 = 0.0f;
    {
      float tH = fmaf(0.25f, dsh[j][a0i], Sc[a0i]);
      tH = fmaf((1.0f / 3.0f) * dsh[j][b0i], tH, Sc[5 + s2_0]);
      tH = fmaf(0.5f * dsh[j][c0i], tH, Sc[30 + s3_0]);
      n4_0 = fmaf(dsh[j][d0i], tH, Sc[155 + x0]);
    }
    if (has1) {
      float tH = fmaf(0.25f, dsh[j][a1i], Sc[a1i]);
      tH = fmaf((1.0f / 3.0f) * dsh[j][b1i], tH, Sc[5 + s2_1]);
      tH = fmaf(0.5f * dsh[j][c1i], tH, Sc[30 + s3_1]);
      n4_1 = fmaf(dsh[j][d1i], tH, Sc[155 + x1]);
    }
    if (hasL3) {
      float tH = fmaf((1.0f / 3.0f), dsh[j][ya], Sc[ya]);
      tH = fmaf(0.5f * dsh[j][yb], tH, Sc[5 + ya * 5 + yb]);
      n3 = fmaf(dsh[j][yc], tH, Sc[30 + tid]);
    }
    if (hasL2) {
      float tH = fmaf(0.5f, dsh[j][za], Sc[za]);
      n2 = fmaf(dsh[j][zb], tH, Sc[5 + tid]);
    }
    if (hasL1) n1 = Sc[tid] + dsh[j][tid];
    Sn[155 + x0] = n4_0;
    if (has1) Sn[155 + x1] = n4_1;
    if (hasL3) Sn[30 + tid] = n3;
    if (hasL2) Sn[5 + tid] = n2;
    if (hasL1) Sn[tid] = n1;
    __syncthreads();
    c ^= 1;
  }

  float* Pr = P + ((size_t)n * N_SEG + s) * SIG;
  for (int i = tid; i < SIG; i += 320) Pr[i] = S[c][i];
}

// ---------------- Signature phase B: sequential prefix (ping-pong, 1 bar) ---
__global__ __launch_bounds__(640) void prefix_kernel(float* __restrict__ P) {
  int n = blockIdx.x;
  int tid = threadIdx.x;
  __shared__ float A[2][SIG];
  __shared__ float Bs[SIG];

  float* Pn = P + (size_t)n * N_SEG * SIG;
  for (int i = tid; i < SIG; i += 640) A[0][i] = Pn[i];
  int i0 = tid, i1 = tid + 640;
  float r0 = 0.f, r1 = 0.f;
  if (i0 < SIG) r0 = Pn[SIG + i0];
  if (i1 < SIG) r1 = Pn[SIG + i1];

  const int e4 = tid;
  const int q4a = e4 / 125, r125 = e4 % 125, r25 = e4 % 25, r5 = e4 % 5;
  const int e4d5 = e4 / 5, e4d25 = e4 / 25;
  const int e3 = tid;
  const int e3a = e3 / 25, e3r25 = e3 % 25, e3r5 = e3 % 5, e3d5 = e3 / 5;
  const int e2 = tid - 125;
  const int e1 = tid - 150;

  int c = 0;
  for (int s = 1; s < N_SEG; ++s) {
    if (i0 < SIG) Bs[i0] = r0;
    if (i1 < SIG) Bs[i1] = r1;
    __syncthreads();   // Bs ready; prev iter's A[c] writes visible
    if (s + 1 < N_SEG) {
      const float* Pnx = Pn + (size_t)(s + 1) * SIG;
      if (i0 < SIG) r0 = Pnx[i0];
      if (i1 < SIG) r1 = Pnx[i1];
    }
    const float* Ac = A[c];
    float* An = A[c ^ 1];
    float* Po = Pn + (size_t)s * SIG;
    if (tid < 625) {
      float v4 = Ac[155 + e4] + Bs[155 + e4];
      v4 = fmaf(Ac[30 + e4d5], Bs[r5], v4);
      v4 = fmaf(Ac[5 + e4d25], Bs[5 + r25], v4);
      v4 = fmaf(Ac[q4a], Bs[30 + r125], v4);
      An[155 + e4] = v4; Po[155 + e4] = v4;
    }
    if (tid < 125) {
      float v3 = Ac[30 + e3] + Bs[30 + e3];
      v3 = fmaf(Ac[5 + e3d5], Bs[e3r5], v3);
      v3 = fmaf(Ac[e3a], Bs[5 + e3r25], v3);
      An[30 + e3] = v3; Po[30 + e3] = v3;
    } else if (tid < 150) {
      float v2 = Ac[5 + e2] + Bs[5 + e2];
      v2 = fmaf(Ac[e2 / 5], Bs[e2 % 5], v2);
      An[5 + e2] = v2; Po[5 + e2] = v2;
    } else if (tid < 155) {
      float v1 = Ac[e1] + Bs[e1];
      An[e1] = v1; Po[e1] = v1;
    }
    c ^= 1;
  }
}

// ---------------- Signature phase C: stream + emit f16 planes ----------------
// Ping-pong S and row buffers: 1 barrier per time-step; store of row t-1
// overlaps iteration t's compute.
__global__ __launch_bounds__(320) void emit_kernel(
    const float* __restrict__ batch,
    const float* __restrict__ conv_w,
    const float* __restrict__ conv_b,
    const float* __restrict__ P,
    _Float16* __restrict__ c1,
    _Float16* __restrict__ c2) {
  int s = blockIdx.x;
  int n = blockIdx.y;
  int tid = threadIdx.x;

  __shared__ float S[2][SIG];
  __shared__ float bc[(SEG_LEN + 1) * CH];
  __shared__ float dsh[SEG_LEN][CH];
  __shared__ __align__(16) _Float16 row1[2][KP];
  __shared__ __align__(16) _Float16 row2[2][KP];

  if (s == 0) {
    for (int i = tid; i < SIG; i += 320) S[0][i] = 0.0f;
  } else {
    const float* Pr = P + ((size_t)n * N_SEG + (s - 1)) * SIG;
    for (int i = tid; i < SIG; i += 320) S[0][i] = Pr[i];
  }
  if (tid < (SEG_LEN + 1) * CH) {
    int r = s * SEG_LEN - 1 + tid / CH, ch = tid % CH;
    float v = 0.0f;
    if (r >= 0) {
      const float* a = batch + ((size_t)n * T_LEN + r) * IN_D;
      const float* w = conv_w + ch * CH;
      v = conv_b[ch];
      v = fmaf(a[0], w[0], v);
      v = fmaf(a[1], w[1], v);
      v = fmaf(a[2], w[2], v);
      v = fmaf(a[3], w[3], v);
      v = fmaf((float)(r + 1) * (1.0f / T_LEN), w[4], v);
    }
    bc[tid] = v;
  }
  if (tid < KP - SIG) {  // zero the pad tails once (both ping-pong buffers)
    row1[0][SIG + tid] = (_Float16)0.0f;
    row1[1][SIG + tid] = (_Float16)0.0f;
    row2[0][SIG + tid] = (_Float16)0.0f;
    row2[1][SIG + tid] = (_Float16)0.0f;
  }
  __syncthreads();
  if (tid < SEG_LEN * CH) {
    int j = tid / CH, ch = tid % CH;
    dsh[j][ch] = bc[(j + 1) * CH + ch] - bc[j * CH + ch];
  }

  const int x0 = tid;
  const int x1 = tid + 320;
  const bool has1 = (tid < 305);
  const int a0i = x0 / 125, b0i = (x0 / 25) % 5, c0i = (x0 / 5) % 5, d0i = x0 % 5;
  const int a1i = x1 / 125, b1i = (x1 / 25) % 5, c1i = (x1 / 5) % 5, d1i = x1 % 5;
  const int s2_0 = x0 / 25, s3_0 = x0 / 5;
  const int s2_1 = x1 / 25, s3_1 = x1 / 5;
  const bool hasL3 = (tid < 125);
  const int ya = tid / 25, yb = (tid / 5) % 5, yc = tid % 5;
  const bool hasL2 = (tid < 25);
  const int za = tid / 5, zb = tid % 5;
  const bool hasL1 = (tid < CH);
  __syncthreads();

  int c = 0;
  for (int j = 0; j < SEG_LEN; ++j) {
    int t = s * SEG_LEN + j;
    const float* Sc = S[c];
    float* Sn = S[c ^ 1];
    float n4_0, n4_1 = 0.0f, n3 = 0.0f, n2 = 0.0f, n1 = 0.0f;
    {
      float tH = fmaf(0.25f, dsh[j][a0i], Sc[a0i]);
      tH = fmaf((1.0f / 3.0f) * dsh[j][b0i], tH, Sc[5 + s2_0]);
      tH = fmaf(0.5f * dsh[j][c0i], tH, Sc[30 + s3_0]);
      n4_0 = fmaf(dsh[j][d0i], tH, Sc[155 + x0]);
    }
    if (has1) {
      float tH = fmaf(0.25f, dsh[j][a1i], Sc[a1i]);
      tH = fmaf((1.0f / 3.0f) * dsh[j][b1i], tH, Sc[5 + s2_1]);
      tH = fmaf(0.5f * dsh[j][c1i], tH, Sc[30 + s3_1]);
      n4_1 = fmaf(dsh[j][d1i], tH, Sc[155 + x1]);
    }
    if (hasL3) {
      float tH = fmaf((1.0f / 3.0f), dsh[j][ya], Sc[ya]);
      tH = fmaf(0.5f * dsh[j][yb], tH, Sc[5 + ya * 5 + yb]);
      n3 = fmaf(dsh[j][yc], tH, Sc[30 + tid]);
    }
    if (hasL2) {
      float tH = fmaf(0.5f, dsh[j][za], Sc[za]);
      n2 = fmaf(dsh[j][zb], tH, Sc[5 + tid]);
    }
    if (hasL1) n1 = Sc[tid] + dsh[j][tid];

    // overlapped store of the PREVIOUS row (completed at last barrier)
    if (j > 0) {
      size_t base = ((size_t)n * T_LEN + (t - 1)) * KP;
      if (tid < 100) {
        *(float4*)(c1 + base + tid * 8) = *(const float4*)&row1[c][tid * 8];
      } else if (tid < 200) {
        int cc = tid - 100;
        *(float4*)(c2 + base + cc * 8) = *(const float4*)&row2[c][cc * 8];
      }
    }

    // commit state + build scaled f16 row into the OTHER buffers
    Sn[155 + x0] = n4_0;
    if (has1) Sn[155 + x1] = n4_1;
    if (hasL3) Sn[30 + tid] = n3;
    if (hasL2) Sn[5 + tid] = n2;
    if (hasL1) Sn[tid] = n1;

    float z = (t == 0) ? 0.0f : 1.0f;
    {
      float v = n4_0 * SC_L4 * z;
      _Float16 h = (_Float16)v;
      row1[c ^ 1][155 + x0] = h; row2[c ^ 1][155 + x0] = (_Float16)(v - (float)h);
    }
    if (has1) {
      float v = n4_1 * SC_L4 * z;
      _Float16 h = (_Float16)v;
      row1[c ^ 1][155 + x1] = h; row2[c ^ 1][155 + x1] = (_Float16)(v - (float)h);
    }
    if (hasL3) {
      float v = n3 * SC_L3 * z;
      _Float16 h = (_Float16)v;
      row1[c ^ 1][30 + tid] = h; row2[c ^ 1][30 + tid] = (_Float16)(v - (float)h);
    }
    if (hasL2) {
      float v = n2 * SC_L2 * z;
      _Float16 h = (_Float16)v;
      row1[c ^ 1][5 + tid] = h; row2[c ^ 1][5 + tid] = (_Float16)(v - (float)h);
    }
    if (hasL1) {
      float v = n1 * SC_L1 * z;
      _Float16 h = (_Float16)v;
      row1[c ^ 1][tid] = h; row2[c ^ 1][tid] = (_Float16)(v - (float)h);
    }
    __syncthreads();
    c ^= 1;
  }
  // final row (t = s*SEG_LEN + 15)
  {
    size_t base = ((size_t)n * T_LEN + (s * SEG_LEN + SEG_LEN - 1)) * KP;
    if (tid < 100) {
      *(float4*)(c1 + base + tid * 8) = *(const float4*)&row1[c][tid * 8];
    } else if (tid < 200) {
      int cc = tid - 100;
      *(float4*)(c2 + base + cc * 8) = *(const float4*)&row2[c][cc * 8];
    }
  }
}

// ---------------- W plane conversion (scaled, padded to 896x800) -------------
__global__ __launch_bounds__(256) void wconv_kernel(
    const float* __restrict__ W,
    _Float16* __restrict__ w1,
    _Float16* __restrict__ w2) {
  int idx = blockIdx.x * blockDim.x + threadIdx.x;
  if (idx >= 896 * KP) return;
  int nn = idx / KP, k = idx % KP;
  float v = 0.0f;
  if (nn < SIG && k < SIG) {
    float sc = (k < 5) ? 1.0f : (k < 30) ? 4.0f : (k < 155) ? 16.0f : 64.0f;
    v = W[(size_t)nn * SIG + k] * sc;
  }
  _Float16 h = (_Float16)v;
  w1[idx] = h;
  w2[idx] = (_Float16)(v - (float)h);
}

// ---------------- MFMA GEMM: out = tanh((c1+c2)*(w1+w2)^T + b) ---------------
// Round 8: R7 + REGISTER DOUBLE-BUFFERED FRAGMENTS. R7's remaining stall: each
// K-step's MFMAs depend on that step's ds_reads; post-barrier all 8 waves
// convoy on the LDS pipe (~2100 cyc) and the last-served waves' MFMAs run
// after it -> K-step ~ T_lds + T_mfma_tail = 4663 cyc, MfmaUtil 36%.
// Now: step k reads tile k+1's frags into the ALTERNATE register set (X/Y)
// while the 48 MFMAs consume tile k's frags already in registers. Post-barrier
// MFMAs start immediately; LDS drains under them. The pre-barrier waitcnt is
// vmcnt(6)+lgkmcnt(0): lgkm drain restores the "my reads complete before I
// pass the barrier" invariant (overwriting stage is >=1 barrier later = safe).
// X/Y alternate textually (no runtime register indexing). 1 barrier/K-step.
__global__ __launch_bounds__(512, 2) void gemm_mfma(
    const _Float16* __restrict__ A1p, const _Float16* __restrict__ A2p,
    const _Float16* __restrict__ B1p, const _Float16* __restrict__ B2p,
    const float* __restrict__ bias, float* __restrict__ out) {
  __shared__ _Float16 Al[3][2][256 * 32];  // [buf][plane] : 96 KB
  __shared__ _Float16 Bl[3][2][128 * 32];  // [buf][plane] : 48 KB

  int tid = threadIdx.x;
  int lane = tid & 63, wid = tid >> 6;
  int wm = wid >> 1, wn = wid & 1;

  // XCD-bijective swizzle: the 7 n-siblings of each m-tile share one XCD.
  int b = blockIdx.x;
  int xcd = b & 7, sidx = b >> 3;
  int mt = (sidx / 7) * 8 + xcd;
  int nt = sidx % 7;
  int m0 = mt * 256;
  int n0 = nt * 128;

  f32x4 acc[4][4];
#pragma unroll
  for (int i = 0; i < 4; ++i)
#pragma unroll
    for (int j = 0; j < 4; ++j) acc[i][j] = (f32x4){0.f, 0.f, 0.f, 0.f};

  int sr = lane >> 2, scn = lane & 3;
  int swst = (sr ^ (sr >> 2)) & 3;
  int qg = scn ^ swst;          // pre-swizzled global chunk (LDS stays linear)
  int fr = lane & 15, fq = lane >> 4;
  int swf = (fr ^ (fr >> 2)) & 3;
  int fchunk = fq ^ swf;        // matching read-side swizzle

  auto stageA = [&](int kb, int buf, int i) {
    int k0 = kb * 32;
    int linear = wid * 4 + i;          // 0..31
    int plane = linear >> 4, grp = linear & 15;
    size_t g = (size_t)(m0 + grp * 16 + sr) * KP + k0 + qg * 8;
    const _Float16* src = (plane ? A2p : A1p) + g;
    __builtin_amdgcn_global_load_lds((as1cp)src, (as3p)(&Al[buf][plane][grp * 512]), 16, 0, 0);
  };
  auto stageB = [&](int kb, int buf, int i) {
    int k0 = kb * 32;
    int linear = wid * 2 + i;          // 0..15
    int plane = linear >> 3, grp = linear & 7;
    size_t g = (size_t)(n0 + grp * 16 + sr) * KP + k0 + qg * 8;
    const _Float16* src = (plane ? B2p : B1p) + g;
    __builtin_amdgcn_global_load_lds((as1cp)src, (as3p)(&Bl[buf][plane][grp * 512]), 16, 0, 0);
  };

  // two fragment register sets (textual alternation; rule: no runtime idx)
  f16x8 xa1[4], xa2[4], xb1[4], xb2[4];
  f16x8 ya1[4], ya2[4], yb1[4], yb2[4];

#define READF(A1v, A2v, B1v, B2v, rbuf)                              \
  {                                                                  \
    _Pragma("unroll") for (int tm = 0; tm < 4; ++tm) {               \
      int off = (wm * 64 + tm * 16 + fr) * 32 + fchunk * 8;          \
      A1v[tm] = *(const f16x8*)&Al[rbuf][0][off];                    \
      A2v[tm] = *(const f16x8*)&Al[rbuf][1][off];                    \
    }                                                                \
    _Pragma("unroll") for (int tn = 0; tn < 4; ++tn) {               \
      int off = (wn * 64 + tn * 16 + fr) * 32 + fchunk * 8;          \
      B1v[tn] = *(const f16x8*)&Bl[rbuf][0][off];                    \
      B2v[tn] = *(const f16x8*)&Bl[rbuf][1][off];                    \
    }                                                                \
  }

#define MFMAS(A1v, A2v, B1v, B2v)                                                                     \
  __builtin_amdgcn_s_setprio(1);                                                                      \
  _Pragma("unroll") for (int tn = 0; tn < 4; ++tn) {                                                  \
    _Pragma("unroll") for (int tm = 0; tm < 4; ++tm) {                                                \
      acc[tm][tn] = __builtin_amdgcn_mfma_f32_16x16x32_f16(A1v[tm], B1v[tn], acc[tm][tn], 0, 0, 0);   \
      acc[tm][tn] = __builtin_amdgcn_mfma_f32_16x16x32_f16(A1v[tm], B2v[tn], acc[tm][tn], 0, 0, 0);   \
      acc[tm][tn] = __builtin_amdgcn_mfma_f32_16x16x32_f16(A2v[tm], B1v[tn], acc[tm][tn], 0, 0, 0);   \
    }                                                                                                 \
  }                                                                                                   \
  __builtin_amdgcn_s_setprio(0);

  // prologue: stage tiles 0,1; wait tile 0; read its frags -> X
#pragma unroll
  for (int i = 0; i < 4; ++i) stageA(0, 0, i);
#pragma unroll
  for (int i = 0; i < 2; ++i) stageB(0, 0, i);
#pragma unroll
  for (int i = 0; i < 4; ++i) stageA(1, 1, i);
#pragma unroll
  for (int i = 0; i < 2; ++i) stageB(1, 1, i);
  VMCNT(6);
  __builtin_amdgcn_s_barrier();
  __builtin_amdgcn_sched_barrier(0);
  READF(xa1, xa2, xb1, xb2, 0);

  // BODY(kb): [stage kb+2] -> waitcnt(vm, lgkm0) -> barrier -> read kb+1 into
  // NXT -> 48 MFMA on CUR. rb/sb tracked incrementally mod 3.
  int rb = 1, sb = 2;
#define BODY(kb, CA1, CA2, CB1, CB2, NA1, NA2, NB1, NB2)             \
  {                                                                  \
    if ((kb) + 2 < 25) {                                             \
      stageA((kb) + 2, sb, 0); stageA((kb) + 2, sb, 1);              \
      stageA((kb) + 2, sb, 2); stageA((kb) + 2, sb, 3);              \
      stageB((kb) + 2, sb, 0); stageB((kb) + 2, sb, 1);              \
      asm volatile("s_waitcnt vmcnt(6) lgkmcnt(0)" ::: "memory");    \
    } else {                                                         \
      asm volatile("s_waitcnt vmcnt(0) lgkmcnt(0)" ::: "memory");    \
    }                                                                \
    __builtin_amdgcn_s_barrier();                                    \
    __builtin_amdgcn_sched_barrier(0);                               \
    READF(NA1, NA2, NB1, NB2, rb);                                   \
    __builtin_amdgcn_sched_barrier(0);                               \
    MFMAS(CA1, CA2, CB1, CB2);                                       \
    rb = rb + 1; if (rb == 3) rb = 0;                                \
    sb = sb + 1; if (sb == 3) sb = 0;                                \
  }

#pragma unroll 1
  for (int kk = 0; kk < 12; ++kk) {  // covers kb = 0..23
    int k0 = kk * 2;
    BODY(k0,     xa1, xa2, xb1, xb2, ya1, ya2, yb1, yb2);
    BODY(k0 + 1, ya1, ya2, yb1, yb2, xa1, xa2, xb1, xb2);
  }
  // kb = 24: pure MFMA on X (tile 24 read at kb=23); nothing left to stage
  MFMAS(xa1, xa2, xb1, xb2);
#undef BODY
#undef READF
#undef MFMAS

  __syncthreads();  // all frag reads done; LDS reusable for epilogue

  // epilogue: bias + fast tanh, per-wave LDS transpose, float4 stores
  float* ep = (float*)(&Al[0][0][0]) + wid * 2112;  // 32x66 f32 per wave

  float bv[4];
#pragma unroll
  for (int tn = 0; tn < 4; ++tn) {
    int nn = n0 + wn * 64 + tn * 16 + fr;
    bv[tn] = (nn < SIG) ? bias[nn] : 0.0f;
  }
#pragma unroll
  for (int h = 0; h < 2; ++h) {
#pragma unroll
    for (int tm2 = 0; tm2 < 2; ++tm2) {
      int tm = h * 2 + tm2;
#pragma unroll
      for (int tn = 0; tn < 4; ++tn) {
#pragma unroll
        for (int r = 0; r < 4; ++r) {
          int lr = tm2 * 16 + fq * 4 + r;  // 0..31
          int lc = tn * 16 + fr;           // 0..63
          ep[lr * 66 + lc] = fast_tanh(acc[tm][tn][r] + bv[tn]);
        }
      }
    }
    // wave-synchronous readout: 32 rows x 64 cols, float4 per 4 cols
#pragma unroll
    for (int p = 0; p < 2; ++p) {
      int lr = lane & 31;
      int ck = (lane >> 5) * 2 + p;  // 0..3 (16-col chunk)
      int gm = m0 + wm * 64 + h * 32 + lr;
      int gc0 = n0 + wn * 64 + ck * 16;
#pragma unroll
      for (int q = 0; q < 4; ++q) {
        int col = gc0 + q * 4;
        if (col + 3 < SIG) {
          *(float4*)(out + (size_t)gm * SIG + col) =
              *(const float4*)&ep[lr * 66 + ck * 16 + q * 4];
        } else if (col < SIG) {
#pragma unroll
          for (int e = 0; e < 4; ++e) {
            int c2 = col + e;
            if (c2 < SIG) out[(size_t)gm * SIG + c2] = ep[lr * 66 + ck * 16 + q * 4 + e];
          }
        }
      }
    }
  }
}

// ================= FALLBACK PATH (round-1, fp32) =============================
__global__ __launch_bounds__(320) void sig_kernel_fb(
    const float* __restrict__ b_in, float* __restrict__ c_out) {
  int n = blockIdx.x;
  int tid = threadIdx.x;
  __shared__ float S[SIG];
  __shared__ float bc[64 * CH];
  __shared__ float dsh[CH];
  __shared__ float pb[CH];
  for (int i = tid; i < SIG; i += 320) S[i] = 0.0f;
  if (tid < CH) pb[tid] = 0.0f;
  const float* bn = b_in + (size_t)n * T_LEN * CH;
  float* cn = c_out + (size_t)n * T_LEN * SIG;
  const int x0 = tid, x1 = tid + 320;
  const bool has1 = (tid < 305);
  const int a0i = x0 / 125, b0i = (x0 / 25) % 5, c0i = (x0 / 5) % 5, d0i = x0 % 5;
  const int a1i = x1 / 125, b1i = (x1 / 25) % 5, c1i = (x1 / 5) % 5, d1i = x1 % 5;
  const int s2_0 = x0 / 25, s3_0 = x0 / 5, s2_1 = x1 / 25, s3_1 = x1 / 5;
  const bool hasL3 = (tid < 125);
  const int ya = tid / 25, yb = (tid / 5) % 5, yc = tid % 5;
  const bool hasL2 = (tid < 25);
  const int za = tid / 5, zb = tid % 5;
  const bool hasL1 = (tid < CH);
  for (int t = 0; t < T_LEN; ++t) {
    if ((t & 63) == 0) {
      __syncthreads();
      bc[tid] = bn[t * CH + tid];
      __syncthreads();
    }
    if (tid < CH) {
      float cur = bc[(t & 63) * CH + tid];
      dsh[tid] = cur - pb[tid];
      pb[tid] = cur;
    }
    __syncthreads();
    float n4_0, n4_1 = 0.0f, n3 = 0.0f, n2 = 0.0f, n1 = 0.0f;
    {
      float tH = fmaf(0.25f, dsh[a0i], S[a0i]);
      tH = fmaf((1.0f / 3.0f) * dsh[b0i], tH, S[5 + s2_0]);
      tH = fmaf(0.5f * dsh[c0i], tH, S[30 + s3_0]);
      n4_0 = fmaf(dsh[d0i], tH, S[155 + x0]);
    }
    if (has1) {
      float tH = fmaf(0.25f, dsh[a1i], S[a1i]);
      tH = fmaf((1.0f / 3.0f) * dsh[b1i], tH, S[5 + s2_1]);
      tH = fmaf(0.5f * dsh[c1i], tH, S[30 + s3_1]);
      n4_1 = fmaf(dsh[d1i], tH, S[155 + x1]);
    }
    if (hasL3) {
      float tH = fmaf((1.0f / 3.0f), dsh[ya], S[ya]);
      tH = fmaf(0.5f * dsh[yb], tH, S[5 + ya * 5 + yb]);
      n3 = fmaf(dsh[yc], tH, S[30 + tid]);
    }
    if (hasL2) {
      float tH = fmaf(0.5f, dsh[za], S[za]);
      n2 = fmaf(dsh[zb], tH, S[5 + tid]);
    }
    if (hasL1) n1 = S[tid] + dsh[tid];
    __syncthreads();
    S[155 + x0] = n4_0;
    if (has1) S[155 + x1] = n4_1;
    if (hasL3) S[30 + tid] = n3;
    if (hasL2) S[5 + tid] = n2;
    if (hasL1) S[tid] = n1;
    float* crow = cn + (size_t)t * SIG;
    float z = (t == 0) ? 0.0f : 1.0f;
    crow[155 + x0] = n4_0 * z;
    if (has1) crow[155 + x1] = n4_1 * z;
    if (hasL3) crow[30 + tid] = n3 * z;
    if (hasL2) crow[5 + tid] = n2 * z;
    if (hasL1) crow[tid] = n1 * z;
    __syncthreads();
  }
}

#define BM 256
#define BN 64
#define BK 16
__global__ __launch_bounds__(256) void gemm_tanh_fb(
    const float* __restrict__ Cmat, const float* __restrict__ W,
    const float* __restrict__ bias, float* __restrict__ out) {
  __shared__ float As[BK][BM + 4];
  __shared__ float Ws[BK][BN + 4];
  int tid = threadIdx.x;
  int tx = tid & 7, ty = tid >> 3;
  int m0 = blockIdx.x * BM, n0 = blockIdx.y * BN;
  float acc[8][8];
#pragma unroll
  for (int i = 0; i < 8; ++i)
#pragma unroll
    for (int j = 0; j < 8; ++j) acc[i][j] = 0.0f;
  for (int kb = 0; kb < SIG; kb += BK) {
    __syncthreads();
#pragma unroll
    for (int p = 0; p < 4; ++p) {
      int id = tid + p * 256;
      int row = id >> 2, kg = (id & 3) * 4, gk = kb + kg;
      float4 v = make_float4(0.f, 0.f, 0.f, 0.f);
      if (gk < SIG) v = *(const float4*)(Cmat + (size_t)(m0 + row) * SIG + gk);
      As[kg + 0][row] = v.x; As[kg + 1][row] = v.y;
      As[kg + 2][row] = v.z; As[kg + 3][row] = v.w;
    }
    {
      int row = tid >> 2, kg = (tid & 3) * 4, gk = kb + kg, wr = n0 + row;
      float4 v = make_float4(0.f, 0.f, 0.f, 0.f);
      if (gk < SIG && wr < SIG) v = *(const float4*)(W + (size_t)wr * SIG + gk);
      Ws[kg + 0][row] = v.x; Ws[kg + 1][row] = v.y;
      Ws[kg + 2][row] = v.z; Ws[kg + 3][row] = v.w;
    }
    __syncthreads();
#pragma unroll
    for (int k = 0; k < BK; ++k) {
      float af[8], wf[8];
      *(float4*)&af[0] = *(const float4*)&As[k][ty * 8];
      *(float4*)&af[4] = *(const float4*)&As[k][ty * 8 + 4];
      *(float4*)&wf[0] = *(const float4*)&Ws[k][tx * 8];
      *(float4*)&wf[4] = *(const float4*)&Ws[k][tx * 8 + 4];
#pragma unroll
      for (int i = 0; i < 8; ++i)
#pragma unroll
        for (int j = 0; j < 8; ++j) acc[i][j] = fmaf(af[i], wf[j], acc[i][j]);
    }
  }
#pragma unroll
  for (int i = 0; i < 8; ++i) {
    int m = m0 + ty * 8 + i;
    float* orow = out + (size_t)m * SIG;
#pragma unroll
    for (int jj = 0; jj < 8; jj += 4) {
      int col = n0 + tx * 8 + jj;
      if (col < SIG) {
        float4 r;
        r.x = tanhf(acc[i][jj + 0] + bias[col + 0]);
        r.y = tanhf(acc[i][jj + 1] + bias[col + 1]);
        r.z = tanhf(acc[i][jj + 2] + bias[col + 2]);
        r.w = tanhf(acc[i][jj + 3] + bias[col + 3]);
        *(float4*)(orow + col) = r;
      }
    }
  }
}

// ---------------- launch ----------------
extern "C" void kernel_launch(void* const* d_in, const int* in_sizes, int n_in,
                              void* d_out, int out_size, void* d_ws, size_t ws_size,
                              hipStream_t stream) {
  const float* batch = (const float*)d_in[0];
  const float* conv_w = (const float*)d_in[1];
  const float* conv_b = (const float*)d_in[2];
  const float* lin_w = (const float*)d_in[3];
  const float* lin_b = (const float*)d_in[4];
  float* out = (float*)d_out;

  const size_t plane_elems = (size_t)N_B * T_LEN * KP;        // 52,428,800
  const size_t wplane_elems = (size_t)896 * KP;               // 716,800
  const size_t P_elems = (size_t)N_B * N_SEG * SIG;           // 3,194,880
  const size_t bp_elems = (size_t)N_B * T_LEN * CH;           // 327,680
  const size_t need_big = 2 * plane_elems * sizeof(_Float16) +
                          2 * wplane_elems * sizeof(_Float16) +
                          P_elems * sizeof(float);

  if (ws_size >= need_big) {
    _Float16* c1 = (_Float16*)d_ws;
    _Float16* c2 = c1 + plane_elems;
    _Float16* w1 = c2 + plane_elems;
    _Float16* w2 = w1 + wplane_elems;
    float* P = (float*)(w2 + wplane_elems);

    wconv_kernel<<<dim3((896 * KP + 255) / 256), dim3(256), 0, stream>>>(
        lin_w, w1, w2);
    seg_kernel<<<dim3(N_SEG, N_B), dim3(320), 0, stream>>>(batch, conv_w, conv_b, P);
    prefix_kernel<<<dim3(N_B), dim3(640), 0, stream>>>(P);
    emit_kernel<<<dim3(N_SEG, N_B), dim3(320), 0, stream>>>(
        batch, conv_w, conv_b, P, c1, c2);
    gemm_mfma<<<dim3(1792), dim3(512), 0, stream>>>(c1, c2, w1, w2, lin_b, out);
  } else {
    float* b_path = (float*)d_ws;
    float* c_sig = (float*)d_ws + bp_elems;
    conv_kernel<<<dim3((N_B * T_LEN + 255) / 256), dim3(256), 0, stream>>>(
        batch, conv_w, conv_b, b_path);
    sig_kernel_fb<<<dim3(N_B), dim3(320), 0, stream>>>(b_path, c_sig);
    gemm_tanh_fb<<<dim3((N_B * T_LEN) / BM, (SIG + BN - 1) / BN), dim3(256), 0, stream>>>(
        c_sig, lin_w, lin_b, out);
  }
}

// Round 9
// 619.306 us; speedup vs baseline: 1.1757x; 1.0063x over previous
//
#include <hip/hip_runtime.h>
#include <math.h>

#define N_B 64
#define T_LEN 1024
#define IN_D 4
#define CH 5
#define SIG 780
#define KP 800           // padded K for f16 planes
#define SEG_LEN 16
#define N_SEG 64
// level offsets: L1:0, L2:5, L3:30, L4:155
#define SC_L1 1.0f
#define SC_L2 0.25f
#define SC_L3 0.0625f
#define SC_L4 0.015625f

typedef _Float16 f16x8 __attribute__((ext_vector_type(8)));
typedef float f32x4 __attribute__((ext_vector_type(4)));

typedef __attribute__((address_space(1))) const void* as1cp;
typedef __attribute__((address_space(3))) void* as3p;

#define VMCNT(n) asm volatile("s_waitcnt vmcnt(" #n ")" ::: "memory")

__device__ __forceinline__ float fast_tanh(float x) {
  float ax = fabsf(x);
  float e = __expf(-2.0f * ax);
  float r = (1.0f - e) * __builtin_amdgcn_rcpf(1.0f + e);
  return copysignf(r, x);
}

// ---------------- Kernel 1 (fallback only): time-aug + pointwise conv -------
__global__ __launch_bounds__(256) void conv_kernel(
    const float* __restrict__ batch,
    const float* __restrict__ conv_w,
    const float* __restrict__ conv_b,
    float* __restrict__ b_out) {
  int idx = blockIdx.x * blockDim.x + threadIdx.x;
  if (idx >= N_B * T_LEN) return;
  int t = idx & (T_LEN - 1);
  const float* a = batch + (size_t)idx * IN_D;
  float a0 = a[0], a1 = a[1], a2 = a[2], a3 = a[3];
  float tm = (float)(t + 1) / (float)T_LEN;
  float* o = b_out + (size_t)idx * CH;
#pragma unroll
  for (int j = 0; j < CH; ++j) {
    const float* w = conv_w + j * CH;
    float r = conv_b[j];
    r = fmaf(tm, w[4], r);
    r = fmaf(a3, w[3], r);
    r = fmaf(a2, w[2], r);
    r = fmaf(a1, w[1], r);
    r = fmaf(a0, w[0], r);
    o[j] = r;
  }
}

// ---------------- Signature phase A: per-segment signatures (conv fused) ----
// Ping-pong LDS state: 1 barrier per time-step.
__global__ __launch_bounds__(320) void seg_kernel(
    const float* __restrict__ batch,
    const float* __restrict__ conv_w,
    const float* __restrict__ conv_b,
    float* __restrict__ P) {
  int s = blockIdx.x;
  int n = blockIdx.y;
  int tid = threadIdx.x;

  __shared__ float S[2][SIG];
  __shared__ float bc[(SEG_LEN + 1) * CH];
  __shared__ float dsh[SEG_LEN][CH];

  for (int i = tid; i < SIG; i += 320) S[0][i] = 0.0f;
  if (tid < (SEG_LEN + 1) * CH) {
    int r = s * SEG_LEN - 1 + tid / CH, ch = tid % CH;
    float v = 0.0f;
    if (r >= 0) {
      const float* a = batch + ((size_t)n * T_LEN + r) * IN_D;
      const float* w = conv_w + ch * CH;
      v = conv_b[ch];
      v = fmaf(a[0], w[0], v);
      v = fmaf(a[1], w[1], v);
      v = fmaf(a[2], w[2], v);
      v = fmaf(a[3], w[3], v);
      v = fmaf((float)(r + 1) * (1.0f / T_LEN), w[4], v);
    }
    bc[tid] = v;
  }
  __syncthreads();
  if (tid < SEG_LEN * CH) {
    int j = tid / CH, ch = tid % CH;
    dsh[j][ch] = bc[(j + 1) * CH + ch] - bc[j * CH + ch];
  }

  const int x0 = tid;
  const int x1 = tid + 320;
  const bool has1 = (tid < 305);
  const int a0i = x0 / 125, b0i = (x0 / 25) % 5, c0i = (x0 / 5) % 5, d0i = x0 % 5;
  const int a1i = x1 / 125, b1i = (x1 / 25) % 5, c1i = (x1 / 5) % 5, d1i = x1 % 5;
  const int s2_0 = x0 / 25, s3_0 = x0 / 5;
  const int s2_1 = x1 / 25, s3_1 = x1 / 5;
  const bool hasL3 = (tid < 125);
  const int ya = tid / 25, yb = (tid / 5) % 5, yc = tid % 5;
  const bool hasL2 = (tid < 25);
  const int za = tid / 5, zb = tid % 5;
  const bool hasL1 = (tid < CH);
  __syncthreads();

  int c = 0;
  for (int j = 0; j < SEG_LEN; ++j) {
    const float* Sc = S[c];
    float* Sn = S[c ^ 1];
    float n4_0, n4_1 = 0.0f, n3 = 0.0f, n2 = 0.0f, n1 = 0.0f;
    {
      float tH = fmaf(0.25f, dsh[j][a0i], Sc[a0i]);
      tH = fmaf((1.0f / 3.0f) * dsh[j][b0i], tH, Sc[5 + s2_0]);
      tH = fmaf(0.5f * dsh[j][c0i], tH, Sc[30 + s3_0]);
      n4_0 = fmaf(dsh[j][d0i], tH, Sc[155 + x0]);
    }
    if (has1) {
      float tH = fmaf(0.25f, dsh[j][a1i], Sc[a1i]);
      tH = fmaf((1.0f / 3.0f) * dsh[j][b1i], tH, Sc[5 + s2_1]);
      tH = fmaf(0.5f * dsh[j][c1i], tH, Sc[30 + s3_1]);
      n4_1 = fmaf(dsh[j][d1i], tH, Sc[155 + x1]);
    }
    if (hasL3) {
      float tH = fmaf((1.0f / 3.0f), dsh[j][ya], Sc[ya]);
      tH = fmaf(0.5f * dsh[j][yb], tH, Sc[5 + ya * 5 + yb]);
      n3 = fmaf(dsh[j][yc], tH, Sc[30 + tid]);
    }
    if (hasL2) {
      float tH = fmaf(0.5f, dsh[j][za], Sc[za]);
      n2 = fmaf(dsh[j][zb], tH, Sc[5 + tid]);
    }
    if (hasL1) n1 = Sc[tid] + dsh[j][tid];
    Sn[155 + x0] = n4_0;
    if (has1) Sn[155 + x1] = n4_1;
    if (hasL3) Sn[30 + tid] = n3;
    if (hasL2) Sn[5 + tid] = n2;
    if (hasL1) Sn[tid] = n1;
    __syncthreads();
    c ^= 1;
  }

  float* Pr = P + ((size_t)n * N_SEG + s) * SIG;
  for (int i = tid; i < SIG; i += 320) Pr[i] = S[c][i];
}

// ---------------- Signature phase B: sequential prefix (ping-pong, 1 bar) ---
__global__ __launch_bounds__(640) void prefix_kernel(float* __restrict__ P) {
  int n = blockIdx.x;
  int tid = threadIdx.x;
  __shared__ float A[2][SIG];
  __shared__ float Bs[SIG];

  float* Pn = P + (size_t)n * N_SEG * SIG;
  for (int i = tid; i < SIG; i += 640) A[0][i] = Pn[i];
  int i0 = tid, i1 = tid + 640;
  float r0 = 0.f, r1 = 0.f;
  if (i0 < SIG) r0 = Pn[SIG + i0];
  if (i1 < SIG) r1 = Pn[SIG + i1];

  const int e4 = tid;
  const int q4a = e4 / 125, r125 = e4 % 125, r25 = e4 % 25, r5 = e4 % 5;
  const int e4d5 = e4 / 5, e4d25 = e4 / 25;
  const int e3 = tid;
  const int e3a = e3 / 25, e3r25 = e3 % 25, e3r5 = e3 % 5, e3d5 = e3 / 5;
  const int e2 = tid - 125;
  const int e1 = tid - 150;

  int c = 0;
  for (int s = 1; s < N_SEG; ++s) {
    if (i0 < SIG) Bs[i0] = r0;
    if (i1 < SIG) Bs[i1] = r1;
    __syncthreads();   // Bs ready; prev iter's A[c] writes visible
    if (s + 1 < N_SEG) {
      const float* Pnx = Pn + (size_t)(s + 1) * SIG;
      if (i0 < SIG) r0 = Pnx[i0];
      if (i1 < SIG) r1 = Pnx[i1];
    }
    const float* Ac = A[c];
    float* An = A[c ^ 1];
    float* Po = Pn + (size_t)s * SIG;
    if (tid < 625) {
      float v4 = Ac[155 + e4] + Bs[155 + e4];
      v4 = fmaf(Ac[30 + e4d5], Bs[r5], v4);
      v4 = fmaf(Ac[5 + e4d25], Bs[5 + r25], v4);
      v4 = fmaf(Ac[q4a], Bs[30 + r125], v4);
      An[155 + e4] = v4; Po[155 + e4] = v4;
    }
    if (tid < 125) {
      float v3 = Ac[30 + e3] + Bs[30 + e3];
      v3 = fmaf(Ac[5 + e3d5], Bs[e3r5], v3);
      v3 = fmaf(Ac[e3a], Bs[5 + e3r25], v3);
      An[30 + e3] = v3; Po[30 + e3] = v3;
    } else if (tid < 150) {
      float v2 = Ac[5 + e2] + Bs[5 + e2];
      v2 = fmaf(Ac[e2 / 5], Bs[e2 % 5], v2);
      An[5 + e2] = v2; Po[5 + e2] = v2;
    } else if (tid < 155) {
      float v1 = Ac[e1] + Bs[e1];
      An[e1] = v1; Po[e1] = v1;
    }
    c ^= 1;
  }
}

// ---------------- Signature phase C: stream + emit f16 planes ----------------
// Ping-pong S and row buffers: 1 barrier per time-step; store of row t-1
// overlaps iteration t's compute.
__global__ __launch_bounds__(320) void emit_kernel(
    const float* __restrict__ batch,
    const float* __restrict__ conv_w,
    const float* __restrict__ conv_b,
    const float* __restrict__ P,
    _Float16* __restrict__ c1,
    _Float16* __restrict__ c2) {
  int s = blockIdx.x;
  int n = blockIdx.y;
  int tid = threadIdx.x;

  __shared__ float S[2][SIG];
  __shared__ float bc[(SEG_LEN + 1) * CH];
  __shared__ float dsh[SEG_LEN][CH];
  __shared__ __align__(16) _Float16 row1[2][KP];
  __shared__ __align__(16) _Float16 row2[2][KP];

  if (s == 0) {
    for (int i = tid; i < SIG; i += 320) S[0][i] = 0.0f;
  } else {
    const float* Pr = P + ((size_t)n * N_SEG + (s - 1)) * SIG;
    for (int i = tid; i < SIG; i += 320) S[0][i] = Pr[i];
  }
  if (tid < (SEG_LEN + 1) * CH) {
    int r = s * SEG_LEN - 1 + tid / CH, ch = tid % CH;
    float v = 0.0f;
    if (r >= 0) {
      const float* a = batch + ((size_t)n * T_LEN + r) * IN_D;
      const float* w = conv_w + ch * CH;
      v = conv_b[ch];
      v = fmaf(a[0], w[0], v);
      v = fmaf(a[1], w[1], v);
      v = fmaf(a[2], w[2], v);
      v = fmaf(a[3], w[3], v);
      v = fmaf((float)(r + 1) * (1.0f / T_LEN), w[4], v);
    }
    bc[tid] = v;
  }
  if (tid < KP - SIG) {  // zero the pad tails once (both ping-pong buffers)
    row1[0][SIG + tid] = (_Float16)0.0f;
    row1[1][SIG + tid] = (_Float16)0.0f;
    row2[0][SIG + tid] = (_Float16)0.0f;
    row2[1][SIG + tid] = (_Float16)0.0f;
  }
  __syncthreads();
  if (tid < SEG_LEN * CH) {
    int j = tid / CH, ch = tid % CH;
    dsh[j][ch] = bc[(j + 1) * CH + ch] - bc[j * CH + ch];
  }

  const int x0 = tid;
  const int x1 = tid + 320;
  const bool has1 = (tid < 305);
  const int a0i = x0 / 125, b0i = (x0 / 25) % 5, c0i = (x0 / 5) % 5, d0i = x0 % 5;
  const int a1i = x1 / 125, b1i = (x1 / 25) % 5, c1i = (x1 / 5) % 5, d1i = x1 % 5;
  const int s2_0 = x0 / 25, s3_0 = x0 / 5;
  const int s2_1 = x1 / 25, s3_1 = x1 / 5;
  const bool hasL3 = (tid < 125);
  const int ya = tid / 25, yb = (tid / 5) % 5, yc = tid % 5;
  const bool hasL2 = (tid < 25);
  const int za = tid / 5, zb = tid % 5;
  const bool hasL1 = (tid < CH);
  __syncthreads();

  int c = 0;
  for (int j = 0; j < SEG_LEN; ++j) {
    int t = s * SEG_LEN + j;
    const float* Sc = S[c];
    float* Sn = S[c ^ 1];
    float n4_0, n4_1 = 0.0f, n3 = 0.0f, n2 = 0.0f, n1 = 0.0f;
    {
      float tH = fmaf(0.25f, dsh[j][a0i], Sc[a0i]);
      tH = fmaf((1.0f / 3.0f) * dsh[j][b0i], tH, Sc[5 + s2_0]);
      tH = fmaf(0.5f * dsh[j][c0i], tH, Sc[30 + s3_0]);
      n4_0 = fmaf(dsh[j][d0i], tH, Sc[155 + x0]);
    }
    if (has1) {
      float tH = fmaf(0.25f, dsh[j][a1i], Sc[a1i]);
      tH = fmaf((1.0f / 3.0f) * dsh[j][b1i], tH, Sc[5 + s2_1]);
      tH = fmaf(0.5f * dsh[j][c1i], tH, Sc[30 + s3_1]);
      n4_1 = fmaf(dsh[j][d1i], tH, Sc[155 + x1]);
    }
    if (hasL3) {
      float tH = fmaf((1.0f / 3.0f), dsh[j][ya], Sc[ya]);
      tH = fmaf(0.5f * dsh[j][yb], tH, Sc[5 + ya * 5 + yb]);
      n3 = fmaf(dsh[j][yc], tH, Sc[30 + tid]);
    }
    if (hasL2) {
      float tH = fmaf(0.5f, dsh[j][za], Sc[za]);
      n2 = fmaf(dsh[j][zb], tH, Sc[5 + tid]);
    }
    if (hasL1) n1 = Sc[tid] + dsh[j][tid];

    // overlapped store of the PREVIOUS row (completed at last barrier)
    if (j > 0) {
      size_t base = ((size_t)n * T_LEN + (t - 1)) * KP;
      if (tid < 100) {
        *(float4*)(c1 + base + tid * 8) = *(const float4*)&row1[c][tid * 8];
      } else if (tid < 200) {
        int cc = tid - 100;
        *(float4*)(c2 + base + cc * 8) = *(const float4*)&row2[c][cc * 8];
      }
    }

    // commit state + build scaled f16 row into the OTHER buffers
    Sn[155 + x0] = n4_0;
    if (has1) Sn[155 + x1] = n4_1;
    if (hasL3) Sn[30 + tid] = n3;
    if (hasL2) Sn[5 + tid] = n2;
    if (hasL1) Sn[tid] = n1;

    float z = (t == 0) ? 0.0f : 1.0f;
    {
      float v = n4_0 * SC_L4 * z;
      _Float16 h = (_Float16)v;
      row1[c ^ 1][155 + x0] = h; row2[c ^ 1][155 + x0] = (_Float16)(v - (float)h);
    }
    if (has1) {
      float v = n4_1 * SC_L4 * z;
      _Float16 h = (_Float16)v;
      row1[c ^ 1][155 + x1] = h; row2[c ^ 1][155 + x1] = (_Float16)(v - (float)h);
    }
    if (hasL3) {
      float v = n3 * SC_L3 * z;
      _Float16 h = (_Float16)v;
      row1[c ^ 1][30 + tid] = h; row2[c ^ 1][30 + tid] = (_Float16)(v - (float)h);
    }
    if (hasL2) {
      float v = n2 * SC_L2 * z;
      _Float16 h = (_Float16)v;
      row1[c ^ 1][5 + tid] = h; row2[c ^ 1][5 + tid] = (_Float16)(v - (float)h);
    }
    if (hasL1) {
      float v = n1 * SC_L1 * z;
      _Float16 h = (_Float16)v;
      row1[c ^ 1][tid] = h; row2[c ^ 1][tid] = (_Float16)(v - (float)h);
    }
    __syncthreads();
    c ^= 1;
  }
  // final row (t = s*SEG_LEN + 15)
  {
    size_t base = ((size_t)n * T_LEN + (s * SEG_LEN + SEG_LEN - 1)) * KP;
    if (tid < 100) {
      *(float4*)(c1 + base + tid * 8) = *(const float4*)&row1[c][tid * 8];
    } else if (tid < 200) {
      int cc = tid - 100;
      *(float4*)(c2 + base + cc * 8) = *(const float4*)&row2[c][cc * 8];
    }
  }
}

// ---------------- W plane conversion (scaled, padded to 896x800) -------------
__global__ __launch_bounds__(256) void wconv_kernel(
    const float* __restrict__ W,
    _Float16* __restrict__ w1,
    _Float16* __restrict__ w2) {
  int idx = blockIdx.x * blockDim.x + threadIdx.x;
  if (idx >= 896 * KP) return;
  int nn = idx / KP, k = idx % KP;
  float v = 0.0f;
  if (nn < SIG && k < SIG) {
    float sc = (k < 5) ? 1.0f : (k < 30) ? 4.0f : (k < 155) ? 16.0f : 64.0f;
    v = W[(size_t)nn * SIG + k] * sc;
  }
  _Float16 h = (_Float16)v;
  w1[idx] = h;
  w2[idx] = (_Float16)(v - (float)h);
}

// ---------------- MFMA GEMM: out = tanh((c1+c2)*(w1+w2)^T + b) ---------------
// Round 9: R7 structure (256x128, 8 waves 64x64, 3 LDS bufs, counted vmcnt(6),
// prefetch depth 2, ONE barrier per K-step, no mid barriers) with the
// s_setprio(1) wrapper REMOVED. Theory: setprio(1) on MFMA-entering waves wins
// issue arbitration and starves the prio-0 waves still issuing ds_reads, so
// the LDS pipe idles during MFMA bursts and the read/MFMA convoy persists
// (K-step ~ T_lds + T_mfma instead of max). m190 measured setprio as a
// regression on non-phase-split GEMM; it has been carried since round 0
// without an A/B. Single-variable edit on the best-known (340us) kernel.
__global__ __launch_bounds__(512, 2) void gemm_mfma(
    const _Float16* __restrict__ A1p, const _Float16* __restrict__ A2p,
    const _Float16* __restrict__ B1p, const _Float16* __restrict__ B2p,
    const float* __restrict__ bias, float* __restrict__ out) {
  __shared__ _Float16 Al[3][2][256 * 32];  // [buf][plane] : 96 KB
  __shared__ _Float16 Bl[3][2][128 * 32];  // [buf][plane] : 48 KB

  int tid = threadIdx.x;
  int lane = tid & 63, wid = tid >> 6;
  int wm = wid >> 1, wn = wid & 1;

  // XCD-bijective swizzle: the 7 n-siblings of each m-tile share one XCD.
  int b = blockIdx.x;
  int xcd = b & 7, sidx = b >> 3;
  int mt = (sidx / 7) * 8 + xcd;
  int nt = sidx % 7;
  int m0 = mt * 256;
  int n0 = nt * 128;

  f32x4 acc[4][4];
#pragma unroll
  for (int i = 0; i < 4; ++i)
#pragma unroll
    for (int j = 0; j < 4; ++j) acc[i][j] = (f32x4){0.f, 0.f, 0.f, 0.f};

  int sr = lane >> 2, scn = lane & 3;
  int swst = (sr ^ (sr >> 2)) & 3;
  int qg = scn ^ swst;          // pre-swizzled global chunk (LDS stays linear)
  int fr = lane & 15, fq = lane >> 4;
  int swf = (fr ^ (fr >> 2)) & 3;
  int fchunk = fq ^ swf;        // matching read-side swizzle

  auto stageA = [&](int kb, int buf, int i) {
    int k0 = kb * 32;
    int linear = wid * 4 + i;          // 0..31
    int plane = linear >> 4, grp = linear & 15;
    size_t g = (size_t)(m0 + grp * 16 + sr) * KP + k0 + qg * 8;
    const _Float16* src = (plane ? A2p : A1p) + g;
    __builtin_amdgcn_global_load_lds((as1cp)src, (as3p)(&Al[buf][plane][grp * 512]), 16, 0, 0);
  };
  auto stageB = [&](int kb, int buf, int i) {
    int k0 = kb * 32;
    int linear = wid * 2 + i;          // 0..15
    int plane = linear >> 3, grp = linear & 7;
    size_t g = (size_t)(n0 + grp * 16 + sr) * KP + k0 + qg * 8;
    const _Float16* src = (plane ? B2p : B1p) + g;
    __builtin_amdgcn_global_load_lds((as1cp)src, (as3p)(&Bl[buf][plane][grp * 512]), 16, 0, 0);
  };

  // prologue: tiles 0 and 1 in flight (12 loads/thread)
#pragma unroll
  for (int i = 0; i < 4; ++i) stageA(0, 0, i);
#pragma unroll
  for (int i = 0; i < 2; ++i) stageB(0, 0, i);
#pragma unroll
  for (int i = 0; i < 4; ++i) stageA(1, 1, i);
#pragma unroll
  for (int i = 0; i < 2; ++i) stageB(1, 1, i);

  int cur = 0;
#pragma unroll 1
  for (int kb = 0; kb < 25; ++kb) {
    int nx = cur + 2; if (nx >= 3) nx -= 3;
    bool pf = (kb + 2 < 25);
    // counted wait: tile kb done, tile kb+1's 6 loads stay in flight
    if (kb < 24) { VMCNT(6); } else { VMCNT(0); }
    __builtin_amdgcn_s_barrier();
    __builtin_amdgcn_sched_barrier(0);
    f16x8 a1f[4], a2f[4], b1f[4], b2f[4];
    // read order: B0, A0..A3, B1..B3 (first 12 MFMAs enabled after 4 reads)
    {
      int off = (wn * 64 + 0 * 16 + fr) * 32 + fchunk * 8;
      b1f[0] = *(const f16x8*)&Bl[cur][0][off];
      b2f[0] = *(const f16x8*)&Bl[cur][1][off];
    }
#pragma unroll
    for (int tm = 0; tm < 4; ++tm) {
      int off = (wm * 64 + tm * 16 + fr) * 32 + fchunk * 8;
      a1f[tm] = *(const f16x8*)&Al[cur][0][off];
      a2f[tm] = *(const f16x8*)&Al[cur][1][off];
    }
#pragma unroll
    for (int tn = 1; tn < 4; ++tn) {
      int off = (wn * 64 + tn * 16 + fr) * 32 + fchunk * 8;
      b1f[tn] = *(const f16x8*)&Bl[cur][0][off];
      b2f[tn] = *(const f16x8*)&Bl[cur][1][off];
    }
    if (pf) {  // issue next-next tile loads; they ride across barriers
      stageA(kb + 2, nx, 0); stageA(kb + 2, nx, 1);
      stageA(kb + 2, nx, 2); stageA(kb + 2, nx, 3);
      stageB(kb + 2, nx, 0); stageB(kb + 2, nx, 1);
    }
    // NO mid barrier, NO setprio: waves free-run; counted lgkmcnt gates each
    // MFMA on its own operands, and equal-priority issue lets read-issuing
    // waves share the pipes with MFMA-ing waves (cross-wave overlap).
#pragma unroll
    for (int tn = 0; tn < 4; ++tn) {
#pragma unroll
      for (int tm = 0; tm < 4; ++tm) {
        acc[tm][tn] = __builtin_amdgcn_mfma_f32_16x16x32_f16(a1f[tm], b1f[tn], acc[tm][tn], 0, 0, 0);
        acc[tm][tn] = __builtin_amdgcn_mfma_f32_16x16x32_f16(a1f[tm], b2f[tn], acc[tm][tn], 0, 0, 0);
        acc[tm][tn] = __builtin_amdgcn_mfma_f32_16x16x32_f16(a2f[tm], b1f[tn], acc[tm][tn], 0, 0, 0);
      }
    }
    cur = cur + 1; if (cur >= 3) cur -= 3;
  }
  __syncthreads();  // all frag reads done; LDS reusable for epilogue

  // epilogue: bias + fast tanh, per-wave LDS transpose, float4 stores
  float* ep = (float*)(&Al[0][0][0]) + wid * 2112;  // 32x66 f32 per wave

  float bv[4];
#pragma unroll
  for (int tn = 0; tn < 4; ++tn) {
    int nn = n0 + wn * 64 + tn * 16 + fr;
    bv[tn] = (nn < SIG) ? bias[nn] : 0.0f;
  }
#pragma unroll
  for (int h = 0; h < 2; ++h) {
#pragma unroll
    for (int tm2 = 0; tm2 < 2; ++tm2) {
      int tm = h * 2 + tm2;
#pragma unroll
      for (int tn = 0; tn < 4; ++tn) {
#pragma unroll
        for (int r = 0; r < 4; ++r) {
          int lr = tm2 * 16 + fq * 4 + r;  // 0..31
          int lc = tn * 16 + fr;           // 0..63
          ep[lr * 66 + lc] = fast_tanh(acc[tm][tn][r] + bv[tn]);
        }
      }
    }
    // wave-synchronous readout: 32 rows x 64 cols, float4 per 4 cols
#pragma unroll
    for (int p = 0; p < 2; ++p) {
      int lr = lane & 31;
      int ck = (lane >> 5) * 2 + p;  // 0..3 (16-col chunk)
      int gm = m0 + wm * 64 + h * 32 + lr;
      int gc0 = n0 + wn * 64 + ck * 16;
#pragma unroll
      for (int q = 0; q < 4; ++q) {
        int col = gc0 + q * 4;
        if (col + 3 < SIG) {
          *(float4*)(out + (size_t)gm * SIG + col) =
              *(const float4*)&ep[lr * 66 + ck * 16 + q * 4];
        } else if (col < SIG) {
#pragma unroll
          for (int e = 0; e < 4; ++e) {
            int c2 = col + e;
            if (c2 < SIG) out[(size_t)gm * SIG + c2] = ep[lr * 66 + ck * 16 + q * 4 + e];
          }
        }
      }
    }
  }
}

// ================= FALLBACK PATH (round-1, fp32) =============================
__global__ __launch_bounds__(320) void sig_kernel_fb(
    const float* __restrict__ b_in, float* __restrict__ c_out) {
  int n = blockIdx.x;
  int tid = threadIdx.x;
  __shared__ float S[SIG];
  __shared__ float bc[64 * CH];
  __shared__ float dsh[CH];
  __shared__ float pb[CH];
  for (int i = tid; i < SIG; i += 320) S[i] = 0.0f;
  if (tid < CH) pb[tid] = 0.0f;
  const float* bn = b_in + (size_t)n * T_LEN * CH;
  float* cn = c_out + (size_t)n * T_LEN * SIG;
  const int x0 = tid, x1 = tid + 320;
  const bool has1 = (tid < 305);
  const int a0i = x0 / 125, b0i = (x0 / 25) % 5, c0i = (x0 / 5) % 5, d0i = x0 % 5;
  const int a1i = x1 / 125, b1i = (x1 / 25) % 5, c1i = (x1 / 5) % 5, d1i = x1 % 5;
  const int s2_0 = x0 / 25, s3_0 = x0 / 5, s2_1 = x1 / 25, s3_1 = x1 / 5;
  const bool hasL3 = (tid < 125);
  const int ya = tid / 25, yb = (tid / 5) % 5, yc = tid % 5;
  const bool hasL2 = (tid < 25);
  const int za = tid / 5, zb = tid % 5;
  const bool hasL1 = (tid < CH);
  for (int t = 0; t < T_LEN; ++t) {
    if ((t & 63) == 0) {
      __syncthreads();
      bc[tid] = bn[t * CH + tid];
      __syncthreads();
    }
    if (tid < CH) {
      float cur = bc[(t & 63) * CH + tid];
      dsh[tid] = cur - pb[tid];
      pb[tid] = cur;
    }
    __syncthreads();
    float n4_0, n4_1 = 0.0f, n3 = 0.0f, n2 = 0.0f, n1 = 0.0f;
    {
      float tH = fmaf(0.25f, dsh[a0i], S[a0i]);
      tH = fmaf((1.0f / 3.0f) * dsh[b0i], tH, S[5 + s2_0]);
      tH = fmaf(0.5f * dsh[c0i], tH, S[30 + s3_0]);
      n4_0 = fmaf(dsh[d0i], tH, S[155 + x0]);
    }
    if (has1) {
      float tH = fmaf(0.25f, dsh[a1i], S[a1i]);
      tH = fmaf((1.0f / 3.0f) * dsh[b1i], tH, S[5 + s2_1]);
      tH = fmaf(0.5f * dsh[c1i], tH, S[30 + s3_1]);
      n4_1 = fmaf(dsh[d1i], tH, S[155 + x1]);
    }
    if (hasL3) {
      float tH = fmaf((1.0f / 3.0f), dsh[ya], S[ya]);
      tH = fmaf(0.5f * dsh[yb], tH, S[5 + ya * 5 + yb]);
      n3 = fmaf(dsh[yc], tH, S[30 + tid]);
    }
    if (hasL2) {
      float tH = fmaf(0.5f, dsh[za], S[za]);
      n2 = fmaf(dsh[zb], tH, S[5 + tid]);
    }
    if (hasL1) n1 = S[tid] + dsh[tid];
    __syncthreads();
    S[155 + x0] = n4_0;
    if (has1) S[155 + x1] = n4_1;
    if (hasL3) S[30 + tid] = n3;
    if (hasL2) S[5 + tid] = n2;
    if (hasL1) S[tid] = n1;
    float* crow = cn + (size_t)t * SIG;
    float z = (t == 0) ? 0.0f : 1.0f;
    crow[155 + x0] = n4_0 * z;
    if (has1) crow[155 + x1] = n4_1 * z;
    if (hasL3) crow[30 + tid] = n3 * z;
    if (hasL2) crow[5 + tid] = n2 * z;
    if (hasL1) crow[tid] = n1 * z;
    __syncthreads();
  }
}

#define BM 256
#define BN 64
#define BK 16
__global__ __launch_bounds__(256) void gemm_tanh_fb(
    const float* __restrict__ Cmat, const float* __restrict__ W,
    const float* __restrict__ bias, float* __restrict__ out) {
  __shared__ float As[BK][BM + 4];
  __shared__ float Ws[BK][BN + 4];
  int tid = threadIdx.x;
  int tx = tid & 7, ty = tid >> 3;
  int m0 = blockIdx.x * BM, n0 = blockIdx.y * BN;
  float acc[8][8];
#pragma unroll
  for (int i = 0; i < 8; ++i)
#pragma unroll
    for (int j = 0; j < 8; ++j) acc[i][j] = 0.0f;
  for (int kb = 0; kb < SIG; kb += BK) {
    __syncthreads();
#pragma unroll
    for (int p = 0; p < 4; ++p) {
      int id = tid + p * 256;
      int row = id >> 2, kg = (id & 3) * 4, gk = kb + kg;
      float4 v = make_float4(0.f, 0.f, 0.f, 0.f);
      if (gk < SIG) v = *(const float4*)(Cmat + (size_t)(m0 + row) * SIG + gk);
      As[kg + 0][row] = v.x; As[kg + 1][row] = v.y;
      As[kg + 2][row] = v.z; As[kg + 3][row] = v.w;
    }
    {
      int row = tid >> 2, kg = (tid & 3) * 4, gk = kb + kg, wr = n0 + row;
      float4 v = make_float4(0.f, 0.f, 0.f, 0.f);
      if (gk < SIG && wr < SIG) v = *(const float4*)(W + (size_t)wr * SIG + gk);
      Ws[kg + 0][row] = v.x; Ws[kg + 1][row] = v.y;
      Ws[kg + 2][row] = v.z; Ws[kg + 3][row] = v.w;
    }
    __syncthreads();
#pragma unroll
    for (int k = 0; k < BK; ++k) {
      float af[8], wf[8];
      *(float4*)&af[0] = *(const float4*)&As[k][ty * 8];
      *(float4*)&af[4] = *(const float4*)&As[k][ty * 8 + 4];
      *(float4*)&wf[0] = *(const float4*)&Ws[k][tx * 8];
      *(float4*)&wf[4] = *(const float4*)&Ws[k][tx * 8 + 4];
#pragma unroll
      for (int i = 0; i < 8; ++i)
#pragma unroll
        for (int j = 0; j < 8; ++j) acc[i][j] = fmaf(af[i], wf[j], acc[i][j]);
    }
  }
#pragma unroll
  for (int i = 0; i < 8; ++i) {
    int m = m0 + ty * 8 + i;
    float* orow = out + (size_t)m * SIG;
#pragma unroll
    for (int jj = 0; jj < 8; jj += 4) {
      int col = n0 + tx * 8 + jj;
      if (col < SIG) {
        float4 r;
        r.x = tanhf(acc[i][jj + 0] + bias[col + 0]);
        r.y = tanhf(acc[i][jj + 1] + bias[col + 1]);
        r.z = tanhf(acc[i][jj + 2] + bias[col + 2]);
        r.w = tanhf(acc[i][jj + 3] + bias[col + 3]);
        *(float4*)(orow + col) = r;
      }
    }
  }
}

// ---------------- launch ----------------
extern "C" void kernel_launch(void* const* d_in, const int* in_sizes, int n_in,
                              void* d_out, int out_size, void* d_ws, size_t ws_size,
                              hipStream_t stream) {
  const float* batch = (const float*)d_in[0];
  const float* conv_w = (const float*)d_in[1];
  const float* conv_b = (const float*)d_in[2];
  const float* lin_w = (const float*)d_in[3];
  const float* lin_b = (const float*)d_in[4];
  float* out = (float*)d_out;

  const size_t plane_elems = (size_t)N_B * T_LEN * KP;        // 52,428,800
  const size_t wplane_elems = (size_t)896 * KP;               // 716,800
  const size_t P_elems = (size_t)N_B * N_SEG * SIG;           // 3,194,880
  const size_t bp_elems = (size_t)N_B * T_LEN * CH;           // 327,680
  const size_t need_big = 2 * plane_elems * sizeof(_Float16) +
                          2 * wplane_elems * sizeof(_Float16) +
                          P_elems * sizeof(float);

  if (ws_size >= need_big) {
    _Float16* c1 = (_Float16*)d_ws;
    _Float16* c2 = c1 + plane_elems;
    _Float16* w1 = c2 + plane_elems;
    _Float16* w2 = w1 + wplane_elems;
    float* P = (float*)(w2 + wplane_elems);

    wconv_kernel<<<dim3((896 * KP + 255) / 256), dim3(256), 0, stream>>>(
        lin_w, w1, w2);
    seg_kernel<<<dim3(N_SEG, N_B), dim3(320), 0, stream>>>(batch, conv_w, conv_b, P);
    prefix_kernel<<<dim3(N_B), dim3(640), 0, stream>>>(P);
    emit_kernel<<<dim3(N_SEG, N_B), dim3(320), 0, stream>>>(
        batch, conv_w, conv_b, P, c1, c2);
    gemm_mfma<<<dim3(1792), dim3(512), 0, stream>>>(c1, c2, w1, w2, lin_b, out);
  } else {
    float* b_path = (float*)d_ws;
    float* c_sig = (float*)d_ws + bp_elems;
    conv_kernel<<<dim3((N_B * T_LEN + 255) / 256), dim3(256), 0, stream>>>(
        batch, conv_w, conv_b, b_path);
    sig_kernel_fb<<<dim3(N_B), dim3(320), 0, stream>>>(b_path, c_sig);
    gemm_tanh_fb<<<dim3((N_B * T_LEN) / BM, (SIG + BN - 1) / BN), dim3(256), 0, stream>>>(
        c_sig, lin_w, lin_b, out);
  }
}